// Round 5
// baseline (647.216 us; speedup 1.0000x reference)
//
#include <hip/hip_runtime.h>
#include <hip/hip_bf16.h>
#include <math.h>

#define D     128
#define NHEAD 4
#define DH    32
#define DFF   512
#define DIN   16
#define MAXDEG 64
#define TN    16

typedef __attribute__((ext_vector_type(8))) short bf16x8;
typedef __attribute__((ext_vector_type(4))) float f32x4;
typedef __hip_bfloat16 bf16;

// 1/sqrt(32) * log2(e): q pre-scaled so attn weight = exp2(q.k)
#define QSCALE_L2E 0.2550348838f

// r13: A-fragments in 16 VGPRs straight from global; best dense config.
// r16: dispatch/traffic elimination outside inner loops works (+22 µs).
// r18: dense kernels rebuilt on global_load_lds + raw s_barrier + counted
//      vmcnt + XOR-swizzled linear LDS. 728->641 µs.
// r19: attn shfl-broadcast of CSR row REGRESSED (bpermute serial chain).
// r20/r21: 512t BM=128 depth-2; spill found+fixed ((512,4) capped VGPR 64).
//      k_ffn 71->53 µs but stuck: staging throughput ~13 B/cyc/CU at only
//      2 blocks/CU — the barrier-locked pipeline exposes round trips.
// r22 (this round): co-residency is the lever (m97: 3 blocks/CU -> ~66
//      B/cyc/CU). k_ffn: 256t BM=64 quarter-stages (8KB) ring-3 + Hsm =
//      40 KB -> 4 blocks/CU. Quarter swizzle gL^((r>>1)&3) (r&3 would
//      8-way bank conflict at 64-B rows). k_gemm: 256t BM=64 again.
//      k_attn: eid zero-init -> unconditional idx prefetch; 4 receivers
//      per wave with cross-receiver ctx prefetch (kills deg->idx->gather
//      serial chain). k_qkv unchanged (r21, passing, not top-5).
#define BMQ 128

#define WAITV(N) asm volatile("s_waitcnt vmcnt(" #N ")" ::: "memory")
#define WAITLGKM asm volatile("s_waitcnt lgkmcnt(0)" ::: "memory")
#define FENCE()  asm volatile("" ::: "memory")
#define BAR() do { FENCE(); __builtin_amdgcn_s_barrier(); FENCE(); } while (0)

__device__ __forceinline__ void gll16(const bf16* g, bf16* l) {
    __builtin_amdgcn_global_load_lds((__attribute__((address_space(1))) void*)g,
                                     (__attribute__((address_space(3))) void*)l,
                                     16, 0, 0);
}

__device__ __forceinline__ ushort bfbits(float f) {
    __hip_bfloat16 b = __float2bfloat16(f);
    return *(ushort*)&b;
}

// ---------------- CSR fill (deg+eid zeroed by k_wt region 25) ---------------
__global__ void k_fill(const int* __restrict__ recv, const int* __restrict__ senders,
                       int* __restrict__ deg, int* __restrict__ eid, int E) {
    int e = blockIdx.x * blockDim.x + threadIdx.x;
    if (e >= E) return;
    int r = recv[e];
    int pos = atomicAdd(&deg[r], 1);
    if (pos < MAXDEG) eid[r * MAXDEG + pos] = senders[e];
}

// ------- weight transpose + bf16 convert + deg/eid zero (26 regions) --------
__global__ void k_wt(const float* __restrict__ wq, const float* __restrict__ wk,
                     const float* __restrict__ wv, const float* __restrict__ wo,
                     const float* __restrict__ w1, const float* __restrict__ w2,
                     const float* __restrict__ encw2,
                     bf16* __restrict__ wqkvT, bf16* __restrict__ woT,
                     bf16* __restrict__ w1T, bf16* __restrict__ w2T,
                     bf16* __restrict__ encw2T, int* __restrict__ deg,
                     int* __restrict__ eid, int N) {
    int r = blockIdx.y;
    if (r == 25) {      // zero deg + eid (runs before k_fill; eid zeroing
                        // makes stale-index loads in k_attn safe)
        int tot = N + N * MAXDEG;
        for (int i = blockIdx.x * blockDim.x + threadIdx.x; i < tot;
             i += 256 * 256) {
            if (i < N) deg[i] = 0;
            else eid[i - N] = 0;
        }
        return;
    }
    const float* src; bf16* dst; int K, Nout;
    if (r < 12) {
        int l = r / 3, sel = r % 3;
        src = (sel == 0 ? wq : sel == 1 ? wk : wv) + (size_t)l * D * D;
        dst = wqkvT + (size_t)l * 3 * D * D + (size_t)sel * D * D;
        K = D; Nout = D;
    } else if (r < 16) {
        int l = r - 12;
        src = wo + (size_t)l * D * D; dst = woT + (size_t)l * D * D; K = D; Nout = D;
    } else if (r < 20) {
        int l = r - 16;
        src = w1 + (size_t)l * D * DFF; dst = w1T + (size_t)l * D * DFF; K = D; Nout = DFF;
    } else if (r < 24) {
        int l = r - 20;
        src = w2 + (size_t)l * DFF * D; dst = w2T + (size_t)l * DFF * D; K = DFF; Nout = D;
    } else {
        src = encw2; dst = encw2T; K = D; Nout = D;
    }
    int total = K * Nout;
    int i = blockIdx.x * blockDim.x + threadIdx.x;
    if (i >= total) return;
    int k = i / Nout, j = i % Nout;
    dst[(size_t)j * K + k] = __float2bfloat16(src[i]);
}

// helper: load this wave's 4 A-fragments (16 rows x 128 cols) from global
__device__ __forceinline__ void load_afrag(const bf16* A, int arow, int quad,
                                           int N, bf16x8* afr) {
    const bf16* ab = A + (size_t)arow * D + quad * 8;
#pragma unroll
    for (int i = 0; i < 4; i++) {
        uint4 v = make_uint4(0u, 0u, 0u, 0u);
        if (arow < N) v = *(const uint4*)(ab + i * 32);
        afr[i] = *(bf16x8*)&v;
    }
}

// ---- stage a full 128x128 tile (32KB), 256 threads: 8 gll/thread ----------
// LDS linear [128][128]; granule(16B) swizzle: LDS (r,gL) <- src (r, gL^(r&15))
__device__ __forceinline__ void stage_full256(bf16* lb, const bf16* src,
                                              int wave, int lane) {
#pragma unroll
    for (int k = 0; k < 8; k++) {
        int gidx = (wave * 8 + k) * 64 + lane;
        int r = gidx >> 4, gL = gidx & 15;
        gll16(src + (size_t)r * 128 + ((gL ^ (r & 15)) * 8),
              lb + (size_t)(wave * 8 + k) * 512);
    }
}

// ---- stage a full 128x128 tile (32KB), 512 threads: 4 gll/thread ----------
__device__ __forceinline__ void stage_full512(bf16* lb, const bf16* src,
                                              int wave, int lane) {
#pragma unroll
    for (int k = 0; k < 4; k++) {
        int gidx = (wave * 4 + k) * 64 + lane;
        int r = gidx >> 4, gL = gidx & 15;
        gll16(src + (size_t)r * 128 + ((gL ^ (r & 15)) * 8),
              lb + (size_t)(wave * 4 + k) * 512);
    }
}

// ---- stage a 128x32 quarter-tile (8KB), 256 threads: 2 gll/thread ---------
// rows 64 B: swizzle gL ^ ((r>>1)&3) spreads lanes over all 32 banks
// (2-way = free); gL ^ (r&3) would 8-way conflict.
__device__ __forceinline__ void stage_q(bf16* lb, const bf16* src, int rs,
                                        int wave, int lane) {
#pragma unroll
    for (int k = 0; k < 2; k++) {
        int gidx = (wave * 2 + k) * 64 + lane;      // 0..511
        int r = gidx >> 2, gL = gidx & 3;           // 128 rows x 4 granules
        gll16(src + (size_t)r * rs + ((gL ^ ((r >> 1) & 3)) * 8),
              lb + (size_t)(wave * 2 + k) * 512);
    }
}

// MFMA over a full swizzled tile: acc[j] += A(afr) * W[128][128]
__device__ __forceinline__ void mfma_tile(const bf16* Wb, const bf16x8* afr,
                                          f32x4* acc, int l16, int quad) {
#pragma unroll
    for (int i = 0; i < 4; i++)
#pragma unroll
        for (int j = 0; j < 8; j++) {
            const bf16* wp = Wb + (size_t)(j * 16 + l16) * 128
                              + (size_t)((((i * 4 + quad)) ^ l16) * 8);
            acc[j] = __builtin_amdgcn_mfma_f32_16x16x32_bf16(afr[i], *(const bf16x8*)wp,
                                                             acc[j], 0, 0, 0);
        }
}

// ---------------- bf16 MFMA GEMM, 64 rows x 128 cols, K=128, 256t -----------
// OPs: 2 RES_LN (wo+ln2), 5 BIAS_LN (encode+ln1_0)
template<int OP>
__global__ __launch_bounds__(256, 4) void k_gemm(
        const bf16* __restrict__ A, const bf16* __restrict__ Bt,
        const float* __restrict__ bias,
        const float* __restrict__ lns, const float* __restrict__ lnb,
        float* x, bf16* outB, int N) {
    __shared__ alignas(16) bf16 Wsm[128 * 128];   // 32 KB -> 4 blocks/CU
    int m0 = blockIdx.x * 64;
    int t = threadIdx.x;
    int wave = t >> 6, lane = t & 63;
    int quad = lane >> 4, l16 = lane & 15;
    int wm = wave * 16;

    bf16x8 afr[4];
    load_afrag(A, m0 + wm + l16, quad, N, afr);
    FENCE();
    stage_full256(Wsm, Bt, wave, lane);
    WAITV(0); BAR();

    int rowb = m0 + wm + quad * 4;
    float xv[8][4];
    if (OP == 2) {   // hoist residual reads: latency hides under MFMA phase
#pragma unroll
        for (int j = 0; j < 8; j++)
#pragma unroll
            for (int r = 0; r < 4; r++) {
                int gr = rowb + r;
                xv[j][r] = (gr < N) ? x[(size_t)gr * D + j * 16 + l16] : 0.f;
            }
    }

    f32x4 acc[8];
#pragma unroll
    for (int j = 0; j < 8; j++) acc[j] = (f32x4){0.f, 0.f, 0.f, 0.f};
    mfma_tile(Wsm, afr, acc, l16, quad);

    float bv[8];
    if (OP == 5) {
#pragma unroll
        for (int j = 0; j < 8; j++) bv[j] = bias[j * 16 + l16];
    }
#pragma unroll
    for (int j = 0; j < 8; j++) {
#pragma unroll
        for (int r = 0; r < 4; r++) {
            int gr = rowb + r;
            if (gr >= N) continue;
            float val = acc[j][r];
            if (OP == 5) val += bv[j];
            if (OP == 2) val += xv[j][r];
            acc[j][r] = val;
        }
    }
    float lsv[8], lbv[8];
#pragma unroll
    for (int j = 0; j < 8; j++) {
        lsv[j] = lns[j * 16 + l16];
        lbv[j] = lnb[j * 16 + l16];
    }
#pragma unroll
    for (int r = 0; r < 4; r++) {
        float s1 = 0.f, s2 = 0.f;
#pragma unroll
        for (int j = 0; j < 8; j++) {
            float v = acc[j][r];
            s1 += v; s2 += v * v;
        }
        s1 += __shfl_xor(s1, 1, 64);  s2 += __shfl_xor(s2, 1, 64);
        s1 += __shfl_xor(s1, 2, 64);  s2 += __shfl_xor(s2, 2, 64);
        s1 += __shfl_xor(s1, 4, 64);  s2 += __shfl_xor(s2, 4, 64);
        s1 += __shfl_xor(s1, 8, 64);  s2 += __shfl_xor(s2, 8, 64);
        float mu = s1 * (1.f / 128.f);
        float var = s2 * (1.f / 128.f) - mu * mu;
        float rinv = rsqrtf(fmaxf(var, 0.f) + 1e-5f);
        int gr = rowb + r;
        if (gr >= N) continue;
#pragma unroll
        for (int j = 0; j < 8; j++) {
            int col = j * 16 + l16;
            float v = acc[j][r];
            x[(size_t)gr * D + col] = v;
            outB[(size_t)gr * D + col] =
                __float2bfloat16((v - mu) * rinv * lsv[j] + lbv[j]);
        }
    }
}

// ---------------- fused QKV: K->V->Q phases, <=2 live acc sets (r21) --------
__global__ __launch_bounds__(512, 2) void k_qkv(
        const bf16* __restrict__ hb, const bf16* __restrict__ wqkvT,
        bf16* __restrict__ qb, bf16* __restrict__ kvb, int N) {
    __shared__ alignas(16) bf16 Wbuf[2][128 * 128];   // 64 KB -> 2 blocks/CU
    int m0 = blockIdx.x * BMQ;
    int t = threadIdx.x;
    int wave = t >> 6, lane = t & 63;
    int quad = lane >> 4, l16 = lane & 15;
    int wm = wave * 16;

    bf16x8 afr[4];
    load_afrag(hb, m0 + wm + l16, quad, N, afr);             // 4 vm (oldest)
    FENCE();
    stage_full512(Wbuf[0], wqkvT + (size_t)D * D, wave, lane);   // K tile
    FENCE();
    stage_full512(Wbuf[1], wqkvT + (size_t)2 * D * D, wave, lane); // V tile
    FENCE();

    int rowb = m0 + wm + quad * 4;
    f32x4 ak[8], acc[8];
#pragma unroll
    for (int j = 0; j < 8; j++) ak[j] = (f32x4){0.f, 0.f, 0.f, 0.f};

    WAITV(4); BAR();                 // afr + K landed; V in flight
    __builtin_amdgcn_s_setprio(1);
    mfma_tile(Wbuf[0], afr, ak, l16, quad);
    __builtin_amdgcn_s_setprio(0);
    BAR();                           // buf0 free
    stage_full512(Wbuf[0], wqkvT, wave, lane);   // Q tile
    FENCE();
#pragma unroll
    for (int j = 0; j < 8; j++) acc[j] = (f32x4){0.f, 0.f, 0.f, 0.f};
    WAITV(4); BAR();                 // V landed; Q in flight
    __builtin_amdgcn_s_setprio(1);
    mfma_tile(Wbuf[1], afr, acc, l16, quad);   // acc = V
    __builtin_amdgcn_s_setprio(0);

    // pack + store kv now (overlaps Q-tile gll latency)
#pragma unroll
    for (int j = 0; j < 8; j++) {
        int col = j * 16 + l16;
#pragma unroll
        for (int r = 0; r < 4; r++) {
            int gr = rowb + r;
            if (gr >= N) continue;
            uint kv = (uint)bfbits(ak[j][r]) | ((uint)bfbits(acc[j][r]) << 16);
            *(uint*)&kvb[((size_t)gr * D + col) * 2] = kv;
        }
    }
    FENCE();
    if (m0 + BMQ <= N) { WAITV(32); } else { WAITV(0); }   // Q tile landed
    BAR();
#pragma unroll
    for (int j = 0; j < 8; j++) acc[j] = (f32x4){0.f, 0.f, 0.f, 0.f};
    __builtin_amdgcn_s_setprio(1);
    mfma_tile(Wbuf[0], afr, acc, l16, quad);   // acc = Q
    __builtin_amdgcn_s_setprio(0);
#pragma unroll
    for (int j = 0; j < 8; j++) {
        int col = j * 16 + l16;
#pragma unroll
        for (int r = 0; r < 4; r++) {
            int gr = rowb + r;
            if (gr >= N) continue;
            qb[(size_t)gr * D + col] = __float2bfloat16(acc[j][r] * QSCALE_L2E);
        }
    }
}

// ---- stage FFN quarter ts (0..31): per c: {W1 q0..q3, W2 q0..q3} ----------
__device__ __forceinline__ void stage_ffn_q(int ts, const bf16* w1T,
                                            const bf16* w2T, bf16* Wb3,
                                            int wave, int lane) {
    int c = ts >> 3, p = ts & 7;
    const bf16* src; int rs;
    if (p < 4) { src = w1T + (size_t)(c * 128) * 128 + p * 32;       rs = 128; }
    else       { src = w2T + (size_t)(c * 128) + (p - 4) * 32;       rs = DFF; }
    stage_q(Wb3 + (size_t)(ts % 3) * (32 * 128), src, rs, wave, lane);
}

// ---------------- fused FFN: 32-stage gll pipeline, ring-3 quarters ---------
// 40 KB LDS -> 4 blocks/CU. x += relu(hb@w1+b1)@w2 + b2; then LN (MODE 0)
// or fused decode (MODE 1)
template<int MODE>
__global__ __launch_bounds__(256, 4) void k_ffn(
        const bf16* __restrict__ hb, const bf16* __restrict__ w1T,
        const float* __restrict__ b1,
        const bf16* __restrict__ w2T, const float* __restrict__ b2,
        const float* __restrict__ lns, const float* __restrict__ lnb,
        const float* __restrict__ dw1, const float* __restrict__ db1,
        const float* __restrict__ dw2, const float* __restrict__ db2,
        float* x, bf16* outB, float* out, int N) {
    __shared__ alignas(16) bf16 Wb3[3][32 * 128];   // 24 KB ring
    __shared__ alignas(16) bf16 Hsm[64 * 128];      // 16 KB (swizzled) => 40 KB
    int m0 = blockIdx.x * 64;
    int t = threadIdx.x;
    int wave = t >> 6, lane = t & 63;
    int quad = lane >> 4, l16 = lane & 15;
    int wm = wave * 16;
    int rowb = m0 + wm + quad * 4;

    // preload all b1 biases: keeps the pipeline free of stray vmem ops
    float b1pre[4][8];
#pragma unroll
    for (int c2 = 0; c2 < 4; c2++)
#pragma unroll
        for (int j = 0; j < 8; j++) b1pre[c2][j] = b1[c2 * 128 + j * 16 + l16];

    bf16x8 afr[4];
    load_afrag(hb, m0 + wm + l16, quad, N, afr);
    FENCE();
    stage_ffn_q(0, w1T, w2T, &Wb3[0][0], wave, lane);
    FENCE();
    stage_ffn_q(1, w1T, w2T, &Wb3[0][0], wave, lane);
    FENCE();

    f32x4 acc2[8], accP[8];
#pragma unroll
    for (int j = 0; j < 8; j++) acc2[j] = (f32x4){0.f, 0.f, 0.f, 0.f};
    float xv[8][4];

    int wswz = (quad ^ ((l16 >> 1) & 3)) * 8;   // W quarter-granule swizzle

#pragma unroll
    for (int s = 0; s < 32; s++) {
        BAR();                       // all waves done reading slot (s-1)%3
        if (s + 2 < 32) {
            stage_ffn_q(s + 2, w1T, w2T, &Wb3[0][0], wave, lane);
            FENCE();
        }
        // own parts of quarter s done; s+1, s+2 in flight (2 ops each)
        if (s < 30) { WAITV(4); } else if (s == 30) { WAITV(2); } else { WAITV(0); }
        BAR();                       // everyone's parts of quarter s landed
        const bf16* Wb = &Wb3[0][0] + (size_t)(s % 3) * (32 * 128);
        int c = s >> 3, p = s & 7;
        if (s == 31) {   // residual prefetch: after last counted wait -> safe
#pragma unroll
            for (int j = 0; j < 8; j++)
#pragma unroll
                for (int r = 0; r < 4; r++) {
                    int gr = rowb + r;
                    xv[j][r] = (gr < N) ? x[(size_t)gr * D + j * 16 + l16] : 0.f;
                }
        }
        if (p < 4) {
            if (p == 0) {
#pragma unroll
                for (int j = 0; j < 8; j++) accP[j] = (f32x4){0.f, 0.f, 0.f, 0.f};
            }
            __builtin_amdgcn_s_setprio(1);
#pragma unroll
            for (int j = 0; j < 8; j++) {
                const bf16* wp = Wb + (size_t)(j * 16 + l16) * 32 + wswz;
                accP[j] = __builtin_amdgcn_mfma_f32_16x16x32_bf16(
                    afr[p], *(const bf16x8*)wp, accP[j], 0, 0, 0);
            }
            __builtin_amdgcn_s_setprio(0);
            if (p == 3) {   // relu+bias -> swizzled Hsm (wave-private rows)
                int rw = wm + quad * 4;
#pragma unroll
                for (int j = 0; j < 8; j++) {
                    int gb = j * 2 + (l16 >> 3), ce = l16 & 7;
#pragma unroll
                    for (int r = 0; r < 4; r++) {
                        int row = rw + r;
                        Hsm[(size_t)row * 128 + (size_t)((gb ^ (row & 15)) * 8) + ce] =
                            __float2bfloat16(fmaxf(accP[j][r] + b1pre[c][j], 0.f));
                    }
                }
                WAITLGKM;   // own ds_writes drained before next-stage reads
            }
        } else {
            int kq = p - 4;
            bf16x8 af2 = *(const bf16x8*)(Hsm + (size_t)(wm + l16) * 128
                              + (size_t)(((kq * 4 + quad) ^ l16) * 8));
            __builtin_amdgcn_s_setprio(1);
#pragma unroll
            for (int j = 0; j < 8; j++) {
                const bf16* wp = Wb + (size_t)(j * 16 + l16) * 32 + wswz;
                acc2[j] = __builtin_amdgcn_mfma_f32_16x16x32_bf16(
                    af2, *(const bf16x8*)wp, acc2[j], 0, 0, 0);
            }
            __builtin_amdgcn_s_setprio(0);
        }
    }

    float bv[8];
#pragma unroll
    for (int j = 0; j < 8; j++) bv[j] = b2[j * 16 + l16];
#pragma unroll
    for (int j = 0; j < 8; j++) {
#pragma unroll
        for (int r = 0; r < 4; r++) {
            int gr = rowb + r;
            if (gr >= N) continue;
            acc2[j][r] += bv[j] + xv[j][r];
        }
    }
    if (MODE == 1) {
        float dw[8][3];
#pragma unroll
        for (int j = 0; j < 8; j++) {
            int col = j * 16 + l16;
#pragma unroll
            for (int cc3 = 0; cc3 < 3; cc3++) dw[j][cc3] = dw1[col * 3 + cc3];
        }
#pragma unroll
        for (int r = 0; r < 4; r++) {
            float s0 = 0.f, s1 = 0.f, s2 = 0.f;
#pragma unroll
            for (int j = 0; j < 8; j++) {
                float v = acc2[j][r];
                s0 += v * dw[j][0]; s1 += v * dw[j][1]; s2 += v * dw[j][2];
            }
            s0 += __shfl_xor(s0, 1, 64); s1 += __shfl_xor(s1, 1, 64); s2 += __shfl_xor(s2, 1, 64);
            s0 += __shfl_xor(s0, 2, 64); s1 += __shfl_xor(s1, 2, 64); s2 += __shfl_xor(s2, 2, 64);
            s0 += __shfl_xor(s0, 4, 64); s1 += __shfl_xor(s1, 4, 64); s2 += __shfl_xor(s2, 4, 64);
            s0 += __shfl_xor(s0, 8, 64); s1 += __shfl_xor(s1, 8, 64); s2 += __shfl_xor(s2, 8, 64);
            int gr = rowb + r;
            if (l16 == 0 && gr < N) {
                float t0 = fmaxf(s0 + db1[0], 0.f);
                float t1 = fmaxf(s1 + db1[1], 0.f);
                float t2 = fmaxf(s2 + db1[2], 0.f);
#pragma unroll
                for (int o = 0; o < 3; o++)
                    out[(size_t)gr * 3 + o] =
                        t0 * dw2[0 * 3 + o] + t1 * dw2[1 * 3 + o] + t2 * dw2[2 * 3 + o] + db2[o];
            }
        }
        return;
    }
    float lsv[8], lbv[8];
#pragma unroll
    for (int j = 0; j < 8; j++) {
        lsv[j] = lns[j * 16 + l16];
        lbv[j] = lnb[j * 16 + l16];
    }
#pragma unroll
    for (int r = 0; r < 4; r++) {
        float s1 = 0.f, s2 = 0.f;
#pragma unroll
        for (int j = 0; j < 8; j++) {
            float v = acc2[j][r];
            s1 += v; s2 += v * v;
        }
        s1 += __shfl_xor(s1, 1, 64);  s2 += __shfl_xor(s2, 1, 64);
        s1 += __shfl_xor(s1, 2, 64);  s2 += __shfl_xor(s2, 2, 64);
        s1 += __shfl_xor(s1, 4, 64);  s2 += __shfl_xor(s2, 4, 64);
        s1 += __shfl_xor(s1, 8, 64);  s2 += __shfl_xor(s2, 8, 64);
        float mu = s1 * (1.f / 128.f);
        float var = s2 * (1.f / 128.f) - mu * mu;
        float rinv = rsqrtf(fmaxf(var, 0.f) + 1e-5f);
        int gr = rowb + r;
        if (gr >= N) continue;
#pragma unroll
        for (int j = 0; j < 8; j++) {
            int col = j * 16 + l16;
            float v = acc2[j][r];
            x[(size_t)gr * D + col] = v;
            outB[(size_t)gr * D + col] = __float2bfloat16((v - mu) * rinv * lsv[j] + lbv[j]);
        }
    }
}

// ---------------- encoder stage 1: hb = bf16(relu(f@w1+b1)) ----------------
__global__ void k_enc1(const float* __restrict__ feat,
                       const float* __restrict__ w1, const float* __restrict__ b1,
                       bf16* __restrict__ hb, int N) {
    __shared__ float fsh[TN][DIN];
    int n0 = blockIdx.x * TN;
    int j = threadIdx.x;            // 0..127
    int nvalid = min(TN, N - n0);
    for (int idx = j; idx < TN * DIN; idx += 128) {
        int n = idx / DIN, i = idx % DIN;
        fsh[n][i] = (n < nvalid) ? feat[(n0 + n) * DIN + i] : 0.f;
    }
    __syncthreads();
    float bb = b1[j];
#pragma unroll
    for (int n = 0; n < TN; n++) {
        float a = bb;
#pragma unroll
        for (int i = 0; i < DIN; i++) a += fsh[n][i] * w1[i * D + j];
        if (n < nvalid) hb[(size_t)(n0 + n) * D + j] = __float2bfloat16(fmaxf(a, 0.f));
    }
}

// ---------------- attention: 4 receivers/wave, cross-receiver prefetch ------
// eid is zero-initialized -> index loads are unconditional/safe; next
// receiver's {indices, deg, q} load while current receiver's kv gathers are
// in flight, removing the deg->idx->gather serial chain from steady state.
__device__ __forceinline__ void attn_edge(uint4 w, bool v, float4 qv,
                                          float& l, float& a0, float& a1,
                                          float& a2, float& a3) {
    float k0 = __uint_as_float(w.x << 16), v0 = __uint_as_float(w.x & 0xFFFF0000u);
    float k1 = __uint_as_float(w.y << 16), v1 = __uint_as_float(w.y & 0xFFFF0000u);
    float k2 = __uint_as_float(w.z << 16), v2 = __uint_as_float(w.z & 0xFFFF0000u);
    float k3 = __uint_as_float(w.w << 16), v3 = __uint_as_float(w.w & 0xFFFF0000u);
    float p = qv.x * k0 + qv.y * k1 + qv.z * k2 + qv.w * k3;
    p += __shfl_xor(p, 1, 64);
    p += __shfl_xor(p, 2, 64);
    p += __shfl_xor(p, 4, 64);
    float e = v ? exp2f(p) : 0.f;
    l += e;
    a0 += e * v0; a1 += e * v1; a2 += e * v2; a3 += e * v3;
}

__device__ __forceinline__ float4 unpackq(uint2 qw) {
    float4 qv;
    qv.x = __uint_as_float(qw.x << 16);
    qv.y = __uint_as_float(qw.x & 0xFFFF0000u);
    qv.z = __uint_as_float(qw.y << 16);
    qv.w = __uint_as_float(qw.y & 0xFFFF0000u);
    return qv;
}

__global__ __launch_bounds__(256) void k_attn(
        const bf16* __restrict__ qb, const uint* __restrict__ kvb,
        const int* __restrict__ deg, const int* __restrict__ eid,
        bf16* __restrict__ out, int N) {
    int wave = threadIdx.x >> 6, lane = threadIdx.x & 63;
    int g = lane & 7, h = (lane >> 3) & 3, slot = lane >> 5;
    int d0 = h * 32 + g * 4;
    int rbase = blockIdx.x * 16 + wave * 4;
    if (rbase >= N) return;
    const uint* kvbase = kvb + d0;

    // ctx for first receiver
    int ssN[8];
    {
        const int* row = eid + (size_t)rbase * MAXDEG;
#pragma unroll
        for (int u = 0; u < 8; u++) ssN[u] = row[u * 2 + slot];
    }
    int cntN = min(deg[rbase], MAXDEG);
    float4 qvN = unpackq(*(const uint2*)(qb + (size_t)rbase * D + d0));

#pragma unroll
    for (int i = 0; i < 4; i++) {
        int r = rbase + i;
        if (r >= N) return;
        int cnt = cntN; float4 qv = qvN;
        // issue first-16 gathers immediately (addresses safe: eid zeroed)
        uint4 w[8];
#pragma unroll
        for (int u = 0; u < 8; u++)
            w[u] = *(const uint4*)(kvbase + (size_t)ssN[u] * D);
        // prefetch next receiver's ctx (overlaps the gathers)
        int rn = r + 1;
        if (i < 3 && rn < N) {
            const int* rowN = eid + (size_t)rn * MAXDEG;
#pragma unroll
            for (int u = 0; u < 8; u++) ssN[u] = rowN[u * 2 + slot];
            cntN = min(deg[rn], MAXDEG);
            qvN = unpackq(*(const uint2*)(qb + (size_t)rn * D + d0));
        }
        float l = 0.f, a0 = 0.f, a1 = 0.f, a2 = 0.f, a3 = 0.f;
#pragma unroll
        for (int u = 0; u < 8; u++)
            attn_edge(w[u], (u * 2 + slot) < cnt, qv, l, a0, a1, a2, a3);
        for (int base = 16; base < cnt; base += 16) {   // rare (deg>16)
            const int* row = eid + (size_t)r * MAXDEG;
            int ss[8]; bool vv[8];
#pragma unroll
            for (int u = 0; u < 8; u++) {
                int e = base + u * 2 + slot;
                vv[u] = e < cnt;
                ss[u] = row[e];            // e<64, zero-inited -> safe
            }
            uint4 w2_[8];
#pragma unroll
            for (int u = 0; u < 8; u++)
                w2_[u] = *(const uint4*)(kvbase + (size_t)ss[u] * D);
#pragma unroll
            for (int u = 0; u < 8; u++)
                attn_edge(w2_[u], vv[u], qv, l, a0, a1, a2, a3);
        }
        l  += __shfl_xor(l, 32, 64);
        a0 += __shfl_xor(a0, 32, 64);
        a1 += __shfl_xor(a1, 32, 64);
        a2 += __shfl_xor(a2, 32, 64);
        a3 += __shfl_xor(a3, 32, 64);
        if (lane < 32) {
            float inv = 1.f / (l + 1e-9f);
            bf16 o[4];
            o[0] = __float2bfloat16(a0 * inv);
            o[1] = __float2bfloat16(a1 * inv);
            o[2] = __float2bfloat16(a2 * inv);
            o[3] = __float2bfloat16(a3 * inv);
            *(uint2*)(out + (size_t)r * D + d0) = *(uint2*)o;
        }
    }
}

extern "C" void kernel_launch(void* const* d_in, const int* in_sizes, int n_in,
                              void* d_out, int out_size, void* d_ws, size_t ws_size,
                              hipStream_t stream) {
    const float* feat    = (const float*)d_in[0];
    const int*   senders = (const int*)d_in[1];
    const int*   recv    = (const int*)d_in[2];
    const float* enc_w1  = (const float*)d_in[3];
    const float* enc_b1  = (const float*)d_in[4];
    const float* enc_w2  = (const float*)d_in[5];
    const float* enc_b2  = (const float*)d_in[6];
    const float* wq      = (const float*)d_in[7];
    const float* wk      = (const float*)d_in[8];
    const float* wv      = (const float*)d_in[9];
    const float* wo      = (const float*)d_in[10];
    const float* ln1_s   = (const float*)d_in[11];
    const float* ln1_b   = (const float*)d_in[12];
    const float* ffn_w1  = (const float*)d_in[13];
    const float* ffn_b1  = (const float*)d_in[14];
    const float* ffn_w2  = (const float*)d_in[15];
    const float* ffn_b2  = (const float*)d_in[16];
    const float* ln2_s   = (const float*)d_in[17];
    const float* ln2_b   = (const float*)d_in[18];
    const float* dec_w1  = (const float*)d_in[19];
    const float* dec_b1  = (const float*)d_in[20];
    const float* dec_w2  = (const float*)d_in[21];
    const float* dec_b2  = (const float*)d_in[22];

    int N = in_sizes[0] / DIN;
    int E = in_sizes[1];

    // workspace layout
    char* p = (char*)d_ws;
    float* x   = (float*)p;  p += (size_t)N * D * 4;        // residual fp32
    bf16*  qb  = (bf16*)p;   p += (size_t)N * D * 2;        // q bf16 (pre-scaled)
    bf16*  kvb = (bf16*)p;   p += (size_t)N * D * 2 * 2;    // (k,v) bf16 interleaved
    bf16*  hb  = (bf16*)p;   p += (size_t)N * D * 2;        // LN out / attn out bf16
    int* deg   = (int*)p;    p += (size_t)N * 4;
    int* eid   = (int*)p;    p += (size_t)N * MAXDEG * 4;
    bf16* wqkvT  = (bf16*)p; p += (size_t)4 * 3 * D * D * 2;
    bf16* woT    = (bf16*)p; p += (size_t)4 * D * D * 2;
    bf16* w1T    = (bf16*)p; p += (size_t)4 * D * DFF * 2;
    bf16* w2T    = (bf16*)p; p += (size_t)4 * DFF * D * 2;
    bf16* encw2T = (bf16*)p; p += (size_t)D * D * 2;

    int gm64 = (N + 63) / 64;     // 782
    int gmQ  = (N + BMQ - 1) / BMQ; // 391

    k_wt<<<dim3(256, 26), 256, 0, stream>>>(wq, wk, wv, wo, ffn_w1, ffn_w2, enc_w2,
                                            wqkvT, woT, w1T, w2T, encw2T, deg, eid, N);
    k_fill<<<(E + 255) / 256, 256, 0, stream>>>(recv, senders, deg, eid, E);
    k_enc1<<<(N + TN - 1) / TN, 128, 0, stream>>>(feat, enc_w1, enc_b1, hb, N);
    // x = hb @ enc_w2 + b2; hb = LN1_0(x)
    k_gemm<5><<<gm64, 256, 0, stream>>>(hb, encw2T, enc_b2, ln1_s, ln1_b, x, hb, N);

    for (int l = 0; l < 4; l++) {
        k_qkv<<<gmQ, 512, 0, stream>>>(hb, wqkvT + (size_t)l * 3 * D * D, qb, kvb, N);
        k_attn<<<(N + 15) / 16, 256, 0, stream>>>(qb, (const uint*)kvb, deg, eid, hb, N);
        // x += hb @ wo; hb = LN2(x)
        k_gemm<2><<<gm64, 256, 0, stream>>>(hb, woT + (size_t)l * D * D,
                                            nullptr, ln2_s + l * D, ln2_b + l * D,
                                            x, hb, N);
        // x += relu(hb@w1+b1)@w2 + b2; then LN1_{l+1} (l<3) or fused decode (l=3)
        if (l < 3)
            k_ffn<0><<<gm64, 256, 0, stream>>>(hb, w1T + (size_t)l * D * DFF,
                                               ffn_b1 + l * DFF,
                                               w2T + (size_t)l * DFF * D, ffn_b2 + l * D,
                                               ln1_s + (l + 1) * D, ln1_b + (l + 1) * D,
                                               nullptr, nullptr, nullptr, nullptr,
                                               x, hb, nullptr, N);
        else
            k_ffn<1><<<gm64, 256, 0, stream>>>(hb, w1T + (size_t)l * D * DFF,
                                               ffn_b1 + l * DFF,
                                               w2T + (size_t)l * DFF * D, ffn_b2 + l * D,
                                               nullptr, nullptr,
                                               dec_w1, dec_b1, dec_w2, dec_b2,
                                               x, nullptr, (float*)d_out, N);
    }
}

// Round 6
// 644.262 us; speedup vs baseline: 1.0046x; 1.0046x over previous
//
#include <hip/hip_runtime.h>
#include <hip/hip_bf16.h>
#include <math.h>

#define D     128
#define NHEAD 4
#define DH    32
#define DFF   512
#define DIN   16
#define MAXDEG 64
#define TN    16

typedef __attribute__((ext_vector_type(8))) short bf16x8;
typedef __attribute__((ext_vector_type(4))) float f32x4;
typedef __hip_bfloat16 bf16;

// 1/sqrt(32) * log2(e): q pre-scaled so attn weight = exp2(q.k)
#define QSCALE_L2E 0.2550348838f

// r13: A-fragments in 16 VGPRs straight from global; best dense config.
// r16: dispatch/traffic elimination outside inner loops works (+22 µs).
// r18: dense kernels rebuilt on global_load_lds + raw s_barrier + counted
//      vmcnt + XOR-swizzled linear LDS. 728->641 µs.
// r19: attn shfl-broadcast of CSR row REGRESSED (bpermute serial chain).
// r20/r21: 512t BM=128 depth-2. SPILL RULE (3 data points): launch_bounds
//      2nd arg >=4 (any block size) -> backend targets 8 waves/SIMD ->
//      64-VGPR cap -> ~230B/thread scratch (WRITE_SIZE 2x, FETCH +20MB).
//      (512,2)=88 VGPR clean; plain (256)=116-128 VGPR clean.
// r22: k_ffn 256t quarter-stage (8KB) ring-3, 40KB LDS; k_attn 4 recv/wave
//      cross-receiver prefetch + eid zero-init. Structure good (51 µs even
//      WITH spill) but (256,4) re-triggered the 64-VGPR spill everywhere.
// r23 (this round): drop the occupancy arg — __launch_bounds__(256) on
//      k_ffn/k_gemm (LDS still caps at 4 blocks/CU; 128 VGPR = 16 waves/CU
//      matches). k_qkv stays (512,2). No other changes (delta attributable).
#define BMQ 128

#define WAITV(N) asm volatile("s_waitcnt vmcnt(" #N ")" ::: "memory")
#define WAITLGKM asm volatile("s_waitcnt lgkmcnt(0)" ::: "memory")
#define FENCE()  asm volatile("" ::: "memory")
#define BAR() do { FENCE(); __builtin_amdgcn_s_barrier(); FENCE(); } while (0)

__device__ __forceinline__ void gll16(const bf16* g, bf16* l) {
    __builtin_amdgcn_global_load_lds((__attribute__((address_space(1))) void*)g,
                                     (__attribute__((address_space(3))) void*)l,
                                     16, 0, 0);
}

__device__ __forceinline__ ushort bfbits(float f) {
    __hip_bfloat16 b = __float2bfloat16(f);
    return *(ushort*)&b;
}

// ---------------- CSR fill (deg+eid zeroed by k_wt region 25) ---------------
__global__ void k_fill(const int* __restrict__ recv, const int* __restrict__ senders,
                       int* __restrict__ deg, int* __restrict__ eid, int E) {
    int e = blockIdx.x * blockDim.x + threadIdx.x;
    if (e >= E) return;
    int r = recv[e];
    int pos = atomicAdd(&deg[r], 1);
    if (pos < MAXDEG) eid[r * MAXDEG + pos] = senders[e];
}

// ------- weight transpose + bf16 convert + deg/eid zero (26 regions) --------
__global__ void k_wt(const float* __restrict__ wq, const float* __restrict__ wk,
                     const float* __restrict__ wv, const float* __restrict__ wo,
                     const float* __restrict__ w1, const float* __restrict__ w2,
                     const float* __restrict__ encw2,
                     bf16* __restrict__ wqkvT, bf16* __restrict__ woT,
                     bf16* __restrict__ w1T, bf16* __restrict__ w2T,
                     bf16* __restrict__ encw2T, int* __restrict__ deg,
                     int* __restrict__ eid, int N) {
    int r = blockIdx.y;
    if (r == 25) {      // zero deg + eid (runs before k_fill; eid zeroing
                        // makes stale-index loads in k_attn safe)
        int tot = N + N * MAXDEG;
        for (int i = blockIdx.x * blockDim.x + threadIdx.x; i < tot;
             i += 256 * 256) {
            if (i < N) deg[i] = 0;
            else eid[i - N] = 0;
        }
        return;
    }
    const float* src; bf16* dst; int K, Nout;
    if (r < 12) {
        int l = r / 3, sel = r % 3;
        src = (sel == 0 ? wq : sel == 1 ? wk : wv) + (size_t)l * D * D;
        dst = wqkvT + (size_t)l * 3 * D * D + (size_t)sel * D * D;
        K = D; Nout = D;
    } else if (r < 16) {
        int l = r - 12;
        src = wo + (size_t)l * D * D; dst = woT + (size_t)l * D * D; K = D; Nout = D;
    } else if (r < 20) {
        int l = r - 16;
        src = w1 + (size_t)l * D * DFF; dst = w1T + (size_t)l * D * DFF; K = D; Nout = DFF;
    } else if (r < 24) {
        int l = r - 20;
        src = w2 + (size_t)l * DFF * D; dst = w2T + (size_t)l * DFF * D; K = DFF; Nout = D;
    } else {
        src = encw2; dst = encw2T; K = D; Nout = D;
    }
    int total = K * Nout;
    int i = blockIdx.x * blockDim.x + threadIdx.x;
    if (i >= total) return;
    int k = i / Nout, j = i % Nout;
    dst[(size_t)j * K + k] = __float2bfloat16(src[i]);
}

// helper: load this wave's 4 A-fragments (16 rows x 128 cols) from global
__device__ __forceinline__ void load_afrag(const bf16* A, int arow, int quad,
                                           int N, bf16x8* afr) {
    const bf16* ab = A + (size_t)arow * D + quad * 8;
#pragma unroll
    for (int i = 0; i < 4; i++) {
        uint4 v = make_uint4(0u, 0u, 0u, 0u);
        if (arow < N) v = *(const uint4*)(ab + i * 32);
        afr[i] = *(bf16x8*)&v;
    }
}

// ---- stage a full 128x128 tile (32KB), 256 threads: 8 gll/thread ----------
// LDS linear [128][128]; granule(16B) swizzle: LDS (r,gL) <- src (r, gL^(r&15))
__device__ __forceinline__ void stage_full256(bf16* lb, const bf16* src,
                                              int wave, int lane) {
#pragma unroll
    for (int k = 0; k < 8; k++) {
        int gidx = (wave * 8 + k) * 64 + lane;
        int r = gidx >> 4, gL = gidx & 15;
        gll16(src + (size_t)r * 128 + ((gL ^ (r & 15)) * 8),
              lb + (size_t)(wave * 8 + k) * 512);
    }
}

// ---- stage a full 128x128 tile (32KB), 512 threads: 4 gll/thread ----------
__device__ __forceinline__ void stage_full512(bf16* lb, const bf16* src,
                                              int wave, int lane) {
#pragma unroll
    for (int k = 0; k < 4; k++) {
        int gidx = (wave * 4 + k) * 64 + lane;
        int r = gidx >> 4, gL = gidx & 15;
        gll16(src + (size_t)r * 128 + ((gL ^ (r & 15)) * 8),
              lb + (size_t)(wave * 4 + k) * 512);
    }
}

// ---- stage a 128x32 quarter-tile (8KB), 256 threads: 2 gll/thread ---------
// rows 64 B: swizzle gL ^ ((r>>1)&3) spreads lanes over all 32 banks
// (2-way = free); gL ^ (r&3) would 8-way conflict.
__device__ __forceinline__ void stage_q(bf16* lb, const bf16* src, int rs,
                                        int wave, int lane) {
#pragma unroll
    for (int k = 0; k < 2; k++) {
        int gidx = (wave * 2 + k) * 64 + lane;      // 0..511
        int r = gidx >> 2, gL = gidx & 3;           // 128 rows x 4 granules
        gll16(src + (size_t)r * rs + ((gL ^ ((r >> 1) & 3)) * 8),
              lb + (size_t)(wave * 2 + k) * 512);
    }
}

// MFMA over a full swizzled tile: acc[j] += A(afr) * W[128][128]
__device__ __forceinline__ void mfma_tile(const bf16* Wb, const bf16x8* afr,
                                          f32x4* acc, int l16, int quad) {
#pragma unroll
    for (int i = 0; i < 4; i++)
#pragma unroll
        for (int j = 0; j < 8; j++) {
            const bf16* wp = Wb + (size_t)(j * 16 + l16) * 128
                              + (size_t)((((i * 4 + quad)) ^ l16) * 8);
            acc[j] = __builtin_amdgcn_mfma_f32_16x16x32_bf16(afr[i], *(const bf16x8*)wp,
                                                             acc[j], 0, 0, 0);
        }
}

// ---------------- bf16 MFMA GEMM, 64 rows x 128 cols, K=128, 256t -----------
// OPs: 2 RES_LN (wo+ln2), 5 BIAS_LN (encode+ln1_0)
template<int OP>
__global__ __launch_bounds__(256) void k_gemm(
        const bf16* __restrict__ A, const bf16* __restrict__ Bt,
        const float* __restrict__ bias,
        const float* __restrict__ lns, const float* __restrict__ lnb,
        float* x, bf16* outB, int N) {
    __shared__ alignas(16) bf16 Wsm[128 * 128];   // 32 KB -> 4 blocks/CU
    int m0 = blockIdx.x * 64;
    int t = threadIdx.x;
    int wave = t >> 6, lane = t & 63;
    int quad = lane >> 4, l16 = lane & 15;
    int wm = wave * 16;

    bf16x8 afr[4];
    load_afrag(A, m0 + wm + l16, quad, N, afr);
    FENCE();
    stage_full256(Wsm, Bt, wave, lane);
    WAITV(0); BAR();

    int rowb = m0 + wm + quad * 4;
    float xv[8][4];
    if (OP == 2) {   // hoist residual reads: latency hides under MFMA phase
#pragma unroll
        for (int j = 0; j < 8; j++)
#pragma unroll
            for (int r = 0; r < 4; r++) {
                int gr = rowb + r;
                xv[j][r] = (gr < N) ? x[(size_t)gr * D + j * 16 + l16] : 0.f;
            }
    }

    f32x4 acc[8];
#pragma unroll
    for (int j = 0; j < 8; j++) acc[j] = (f32x4){0.f, 0.f, 0.f, 0.f};
    mfma_tile(Wsm, afr, acc, l16, quad);

    float bv[8];
    if (OP == 5) {
#pragma unroll
        for (int j = 0; j < 8; j++) bv[j] = bias[j * 16 + l16];
    }
#pragma unroll
    for (int j = 0; j < 8; j++) {
#pragma unroll
        for (int r = 0; r < 4; r++) {
            int gr = rowb + r;
            if (gr >= N) continue;
            float val = acc[j][r];
            if (OP == 5) val += bv[j];
            if (OP == 2) val += xv[j][r];
            acc[j][r] = val;
        }
    }
    float lsv[8], lbv[8];
#pragma unroll
    for (int j = 0; j < 8; j++) {
        lsv[j] = lns[j * 16 + l16];
        lbv[j] = lnb[j * 16 + l16];
    }
#pragma unroll
    for (int r = 0; r < 4; r++) {
        float s1 = 0.f, s2 = 0.f;
#pragma unroll
        for (int j = 0; j < 8; j++) {
            float v = acc[j][r];
            s1 += v; s2 += v * v;
        }
        s1 += __shfl_xor(s1, 1, 64);  s2 += __shfl_xor(s2, 1, 64);
        s1 += __shfl_xor(s1, 2, 64);  s2 += __shfl_xor(s2, 2, 64);
        s1 += __shfl_xor(s1, 4, 64);  s2 += __shfl_xor(s2, 4, 64);
        s1 += __shfl_xor(s1, 8, 64);  s2 += __shfl_xor(s2, 8, 64);
        float mu = s1 * (1.f / 128.f);
        float var = s2 * (1.f / 128.f) - mu * mu;
        float rinv = rsqrtf(fmaxf(var, 0.f) + 1e-5f);
        int gr = rowb + r;
        if (gr >= N) continue;
#pragma unroll
        for (int j = 0; j < 8; j++) {
            int col = j * 16 + l16;
            float v = acc[j][r];
            x[(size_t)gr * D + col] = v;
            outB[(size_t)gr * D + col] =
                __float2bfloat16((v - mu) * rinv * lsv[j] + lbv[j]);
        }
    }
}

// ---------------- fused QKV: K->V->Q phases, <=2 live acc sets (r21) --------
__global__ __launch_bounds__(512, 2) void k_qkv(
        const bf16* __restrict__ hb, const bf16* __restrict__ wqkvT,
        bf16* __restrict__ qb, bf16* __restrict__ kvb, int N) {
    __shared__ alignas(16) bf16 Wbuf[2][128 * 128];   // 64 KB -> 2 blocks/CU
    int m0 = blockIdx.x * BMQ;
    int t = threadIdx.x;
    int wave = t >> 6, lane = t & 63;
    int quad = lane >> 4, l16 = lane & 15;
    int wm = wave * 16;

    bf16x8 afr[4];
    load_afrag(hb, m0 + wm + l16, quad, N, afr);             // 4 vm (oldest)
    FENCE();
    stage_full512(Wbuf[0], wqkvT + (size_t)D * D, wave, lane);   // K tile
    FENCE();
    stage_full512(Wbuf[1], wqkvT + (size_t)2 * D * D, wave, lane); // V tile
    FENCE();

    int rowb = m0 + wm + quad * 4;
    f32x4 ak[8], acc[8];
#pragma unroll
    for (int j = 0; j < 8; j++) ak[j] = (f32x4){0.f, 0.f, 0.f, 0.f};

    WAITV(4); BAR();                 // afr + K landed; V in flight
    __builtin_amdgcn_s_setprio(1);
    mfma_tile(Wbuf[0], afr, ak, l16, quad);
    __builtin_amdgcn_s_setprio(0);
    BAR();                           // buf0 free
    stage_full512(Wbuf[0], wqkvT, wave, lane);   // Q tile
    FENCE();
#pragma unroll
    for (int j = 0; j < 8; j++) acc[j] = (f32x4){0.f, 0.f, 0.f, 0.f};
    WAITV(4); BAR();                 // V landed; Q in flight
    __builtin_amdgcn_s_setprio(1);
    mfma_tile(Wbuf[1], afr, acc, l16, quad);   // acc = V
    __builtin_amdgcn_s_setprio(0);

    // pack + store kv now (overlaps Q-tile gll latency)
#pragma unroll
    for (int j = 0; j < 8; j++) {
        int col = j * 16 + l16;
#pragma unroll
        for (int r = 0; r < 4; r++) {
            int gr = rowb + r;
            if (gr >= N) continue;
            uint kv = (uint)bfbits(ak[j][r]) | ((uint)bfbits(acc[j][r]) << 16);
            *(uint*)&kvb[((size_t)gr * D + col) * 2] = kv;
        }
    }
    FENCE();
    if (m0 + BMQ <= N) { WAITV(32); } else { WAITV(0); }   // Q tile landed
    BAR();
#pragma unroll
    for (int j = 0; j < 8; j++) acc[j] = (f32x4){0.f, 0.f, 0.f, 0.f};
    __builtin_amdgcn_s_setprio(1);
    mfma_tile(Wbuf[0], afr, acc, l16, quad);   // acc = Q
    __builtin_amdgcn_s_setprio(0);
#pragma unroll
    for (int j = 0; j < 8; j++) {
        int col = j * 16 + l16;
#pragma unroll
        for (int r = 0; r < 4; r++) {
            int gr = rowb + r;
            if (gr >= N) continue;
            qb[(size_t)gr * D + col] = __float2bfloat16(acc[j][r] * QSCALE_L2E);
        }
    }
}

// ---- stage FFN quarter ts (0..31): per c: {W1 q0..q3, W2 q0..q3} ----------
__device__ __forceinline__ void stage_ffn_q(int ts, const bf16* w1T,
                                            const bf16* w2T, bf16* Wb3,
                                            int wave, int lane) {
    int c = ts >> 3, p = ts & 7;
    const bf16* src; int rs;
    if (p < 4) { src = w1T + (size_t)(c * 128) * 128 + p * 32;       rs = 128; }
    else       { src = w2T + (size_t)(c * 128) + (p - 4) * 32;       rs = DFF; }
    stage_q(Wb3 + (size_t)(ts % 3) * (32 * 128), src, rs, wave, lane);
}

// ---------------- fused FFN: 32-stage gll pipeline, ring-3 quarters ---------
// 40 KB LDS -> 4 blocks/CU. x += relu(hb@w1+b1)@w2 + b2; then LN (MODE 0)
// or fused decode (MODE 1)
template<int MODE>
__global__ __launch_bounds__(256) void k_ffn(
        const bf16* __restrict__ hb, const bf16* __restrict__ w1T,
        const float* __restrict__ b1,
        const bf16* __restrict__ w2T, const float* __restrict__ b2,
        const float* __restrict__ lns, const float* __restrict__ lnb,
        const float* __restrict__ dw1, const float* __restrict__ db1,
        const float* __restrict__ dw2, const float* __restrict__ db2,
        float* x, bf16* outB, float* out, int N) {
    __shared__ alignas(16) bf16 Wb3[3][32 * 128];   // 24 KB ring
    __shared__ alignas(16) bf16 Hsm[64 * 128];      // 16 KB (swizzled) => 40 KB
    int m0 = blockIdx.x * 64;
    int t = threadIdx.x;
    int wave = t >> 6, lane = t & 63;
    int quad = lane >> 4, l16 = lane & 15;
    int wm = wave * 16;
    int rowb = m0 + wm + quad * 4;

    // preload all b1 biases: keeps the pipeline free of stray vmem ops
    float b1pre[4][8];
#pragma unroll
    for (int c2 = 0; c2 < 4; c2++)
#pragma unroll
        for (int j = 0; j < 8; j++) b1pre[c2][j] = b1[c2 * 128 + j * 16 + l16];

    bf16x8 afr[4];
    load_afrag(hb, m0 + wm + l16, quad, N, afr);
    FENCE();
    stage_ffn_q(0, w1T, w2T, &Wb3[0][0], wave, lane);
    FENCE();
    stage_ffn_q(1, w1T, w2T, &Wb3[0][0], wave, lane);
    FENCE();

    f32x4 acc2[8], accP[8];
#pragma unroll
    for (int j = 0; j < 8; j++) acc2[j] = (f32x4){0.f, 0.f, 0.f, 0.f};
    float xv[8][4];

    int wswz = (quad ^ ((l16 >> 1) & 3)) * 8;   // W quarter-granule swizzle

#pragma unroll
    for (int s = 0; s < 32; s++) {
        BAR();                       // all waves done reading slot (s-1)%3
        if (s + 2 < 32) {
            stage_ffn_q(s + 2, w1T, w2T, &Wb3[0][0], wave, lane);
            FENCE();
        }
        // own parts of quarter s done; s+1, s+2 in flight (2 ops each)
        if (s < 30) { WAITV(4); } else if (s == 30) { WAITV(2); } else { WAITV(0); }
        BAR();                       // everyone's parts of quarter s landed
        const bf16* Wb = &Wb3[0][0] + (size_t)(s % 3) * (32 * 128);
        int c = s >> 3, p = s & 7;
        if (s == 31) {   // residual prefetch: after last counted wait -> safe
#pragma unroll
            for (int j = 0; j < 8; j++)
#pragma unroll
                for (int r = 0; r < 4; r++) {
                    int gr = rowb + r;
                    xv[j][r] = (gr < N) ? x[(size_t)gr * D + j * 16 + l16] : 0.f;
                }
        }
        if (p < 4) {
            if (p == 0) {
#pragma unroll
                for (int j = 0; j < 8; j++) accP[j] = (f32x4){0.f, 0.f, 0.f, 0.f};
            }
            __builtin_amdgcn_s_setprio(1);
#pragma unroll
            for (int j = 0; j < 8; j++) {
                const bf16* wp = Wb + (size_t)(j * 16 + l16) * 32 + wswz;
                accP[j] = __builtin_amdgcn_mfma_f32_16x16x32_bf16(
                    afr[p], *(const bf16x8*)wp, accP[j], 0, 0, 0);
            }
            __builtin_amdgcn_s_setprio(0);
            if (p == 3) {   // relu+bias -> swizzled Hsm (wave-private rows)
                int rw = wm + quad * 4;
#pragma unroll
                for (int j = 0; j < 8; j++) {
                    int gb = j * 2 + (l16 >> 3), ce = l16 & 7;
#pragma unroll
                    for (int r = 0; r < 4; r++) {
                        int row = rw + r;
                        Hsm[(size_t)row * 128 + (size_t)((gb ^ (row & 15)) * 8) + ce] =
                            __float2bfloat16(fmaxf(accP[j][r] + b1pre[c][j], 0.f));
                    }
                }
                WAITLGKM;   // own ds_writes drained before next-stage reads
            }
        } else {
            int kq = p - 4;
            bf16x8 af2 = *(const bf16x8*)(Hsm + (size_t)(wm + l16) * 128
                              + (size_t)(((kq * 4 + quad) ^ l16) * 8));
            __builtin_amdgcn_s_setprio(1);
#pragma unroll
            for (int j = 0; j < 8; j++) {
                const bf16* wp = Wb + (size_t)(j * 16 + l16) * 32 + wswz;
                acc2[j] = __builtin_amdgcn_mfma_f32_16x16x32_bf16(
                    af2, *(const bf16x8*)wp, acc2[j], 0, 0, 0);
            }
            __builtin_amdgcn_s_setprio(0);
        }
    }

    float bv[8];
#pragma unroll
    for (int j = 0; j < 8; j++) bv[j] = b2[j * 16 + l16];
#pragma unroll
    for (int j = 0; j < 8; j++) {
#pragma unroll
        for (int r = 0; r < 4; r++) {
            int gr = rowb + r;
            if (gr >= N) continue;
            acc2[j][r] += bv[j] + xv[j][r];
        }
    }
    if (MODE == 1) {
        float dw[8][3];
#pragma unroll
        for (int j = 0; j < 8; j++) {
            int col = j * 16 + l16;
#pragma unroll
            for (int cc3 = 0; cc3 < 3; cc3++) dw[j][cc3] = dw1[col * 3 + cc3];
        }
#pragma unroll
        for (int r = 0; r < 4; r++) {
            float s0 = 0.f, s1 = 0.f, s2 = 0.f;
#pragma unroll
            for (int j = 0; j < 8; j++) {
                float v = acc2[j][r];
                s0 += v * dw[j][0]; s1 += v * dw[j][1]; s2 += v * dw[j][2];
            }
            s0 += __shfl_xor(s0, 1, 64); s1 += __shfl_xor(s1, 1, 64); s2 += __shfl_xor(s2, 1, 64);
            s0 += __shfl_xor(s0, 2, 64); s1 += __shfl_xor(s1, 2, 64); s2 += __shfl_xor(s2, 2, 64);
            s0 += __shfl_xor(s0, 4, 64); s1 += __shfl_xor(s1, 4, 64); s2 += __shfl_xor(s2, 4, 64);
            s0 += __shfl_xor(s0, 8, 64); s1 += __shfl_xor(s1, 8, 64); s2 += __shfl_xor(s2, 8, 64);
            int gr = rowb + r;
            if (l16 == 0 && gr < N) {
                float t0 = fmaxf(s0 + db1[0], 0.f);
                float t1 = fmaxf(s1 + db1[1], 0.f);
                float t2 = fmaxf(s2 + db1[2], 0.f);
#pragma unroll
                for (int o = 0; o < 3; o++)
                    out[(size_t)gr * 3 + o] =
                        t0 * dw2[0 * 3 + o] + t1 * dw2[1 * 3 + o] + t2 * dw2[2 * 3 + o] + db2[o];
            }
        }
        return;
    }
    float lsv[8], lbv[8];
#pragma unroll
    for (int j = 0; j < 8; j++) {
        lsv[j] = lns[j * 16 + l16];
        lbv[j] = lnb[j * 16 + l16];
    }
#pragma unroll
    for (int r = 0; r < 4; r++) {
        float s1 = 0.f, s2 = 0.f;
#pragma unroll
        for (int j = 0; j < 8; j++) {
            float v = acc2[j][r];
            s1 += v; s2 += v * v;
        }
        s1 += __shfl_xor(s1, 1, 64);  s2 += __shfl_xor(s2, 1, 64);
        s1 += __shfl_xor(s1, 2, 64);  s2 += __shfl_xor(s2, 2, 64);
        s1 += __shfl_xor(s1, 4, 64);  s2 += __shfl_xor(s2, 4, 64);
        s1 += __shfl_xor(s1, 8, 64);  s2 += __shfl_xor(s2, 8, 64);
        float mu = s1 * (1.f / 128.f);
        float var = s2 * (1.f / 128.f) - mu * mu;
        float rinv = rsqrtf(fmaxf(var, 0.f) + 1e-5f);
        int gr = rowb + r;
        if (gr >= N) continue;
#pragma unroll
        for (int j = 0; j < 8; j++) {
            int col = j * 16 + l16;
            float v = acc2[j][r];
            x[(size_t)gr * D + col] = v;
            outB[(size_t)gr * D + col] = __float2bfloat16((v - mu) * rinv * lsv[j] + lbv[j]);
        }
    }
}

// ---------------- encoder stage 1: hb = bf16(relu(f@w1+b1)) ----------------
__global__ void k_enc1(const float* __restrict__ feat,
                       const float* __restrict__ w1, const float* __restrict__ b1,
                       bf16* __restrict__ hb, int N) {
    __shared__ float fsh[TN][DIN];
    int n0 = blockIdx.x * TN;
    int j = threadIdx.x;            // 0..127
    int nvalid = min(TN, N - n0);
    for (int idx = j; idx < TN * DIN; idx += 128) {
        int n = idx / DIN, i = idx % DIN;
        fsh[n][i] = (n < nvalid) ? feat[(n0 + n) * DIN + i] : 0.f;
    }
    __syncthreads();
    float bb = b1[j];
#pragma unroll
    for (int n = 0; n < TN; n++) {
        float a = bb;
#pragma unroll
        for (int i = 0; i < DIN; i++) a += fsh[n][i] * w1[i * D + j];
        if (n < nvalid) hb[(size_t)(n0 + n) * D + j] = __float2bfloat16(fmaxf(a, 0.f));
    }
}

// ---------------- attention: 4 receivers/wave, cross-receiver prefetch ------
// eid is zero-initialized -> index loads are unconditional/safe; next
// receiver's {indices, deg, q} load while current receiver's kv gathers are
// in flight, removing the deg->idx->gather serial chain from steady state.
__device__ __forceinline__ void attn_edge(uint4 w, bool v, float4 qv,
                                          float& l, float& a0, float& a1,
                                          float& a2, float& a3) {
    float k0 = __uint_as_float(w.x << 16), v0 = __uint_as_float(w.x & 0xFFFF0000u);
    float k1 = __uint_as_float(w.y << 16), v1 = __uint_as_float(w.y & 0xFFFF0000u);
    float k2 = __uint_as_float(w.z << 16), v2 = __uint_as_float(w.z & 0xFFFF0000u);
    float k3 = __uint_as_float(w.w << 16), v3 = __uint_as_float(w.w & 0xFFFF0000u);
    float p = qv.x * k0 + qv.y * k1 + qv.z * k2 + qv.w * k3;
    p += __shfl_xor(p, 1, 64);
    p += __shfl_xor(p, 2, 64);
    p += __shfl_xor(p, 4, 64);
    float e = v ? exp2f(p) : 0.f;
    l += e;
    a0 += e * v0; a1 += e * v1; a2 += e * v2; a3 += e * v3;
}

__device__ __forceinline__ float4 unpackq(uint2 qw) {
    float4 qv;
    qv.x = __uint_as_float(qw.x << 16);
    qv.y = __uint_as_float(qw.x & 0xFFFF0000u);
    qv.z = __uint_as_float(qw.y << 16);
    qv.w = __uint_as_float(qw.y & 0xFFFF0000u);
    return qv;
}

__global__ __launch_bounds__(256) void k_attn(
        const bf16* __restrict__ qb, const uint* __restrict__ kvb,
        const int* __restrict__ deg, const int* __restrict__ eid,
        bf16* __restrict__ out, int N) {
    int wave = threadIdx.x >> 6, lane = threadIdx.x & 63;
    int g = lane & 7, h = (lane >> 3) & 3, slot = lane >> 5;
    int d0 = h * 32 + g * 4;
    int rbase = blockIdx.x * 16 + wave * 4;
    if (rbase >= N) return;
    const uint* kvbase = kvb + d0;

    // ctx for first receiver
    int ssN[8];
    {
        const int* row = eid + (size_t)rbase * MAXDEG;
#pragma unroll
        for (int u = 0; u < 8; u++) ssN[u] = row[u * 2 + slot];
    }
    int cntN = min(deg[rbase], MAXDEG);
    float4 qvN = unpackq(*(const uint2*)(qb + (size_t)rbase * D + d0));

#pragma unroll
    for (int i = 0; i < 4; i++) {
        int r = rbase + i;
        if (r >= N) return;
        int cnt = cntN; float4 qv = qvN;
        // issue first-16 gathers immediately (addresses safe: eid zeroed)
        uint4 w[8];
#pragma unroll
        for (int u = 0; u < 8; u++)
            w[u] = *(const uint4*)(kvbase + (size_t)ssN[u] * D);
        // prefetch next receiver's ctx (overlaps the gathers)
        int rn = r + 1;
        if (i < 3 && rn < N) {
            const int* rowN = eid + (size_t)rn * MAXDEG;
#pragma unroll
            for (int u = 0; u < 8; u++) ssN[u] = rowN[u * 2 + slot];
            cntN = min(deg[rn], MAXDEG);
            qvN = unpackq(*(const uint2*)(qb + (size_t)rn * D + d0));
        }
        float l = 0.f, a0 = 0.f, a1 = 0.f, a2 = 0.f, a3 = 0.f;
#pragma unroll
        for (int u = 0; u < 8; u++)
            attn_edge(w[u], (u * 2 + slot) < cnt, qv, l, a0, a1, a2, a3);
        for (int base = 16; base < cnt; base += 16) {   // rare (deg>16)
            const int* row = eid + (size_t)r * MAXDEG;
            int ss[8]; bool vv[8];
#pragma unroll
            for (int u = 0; u < 8; u++) {
                int e = base + u * 2 + slot;
                vv[u] = e < cnt;
                ss[u] = row[e];            // e<64, zero-inited -> safe
            }
            uint4 w2_[8];
#pragma unroll
            for (int u = 0; u < 8; u++)
                w2_[u] = *(const uint4*)(kvbase + (size_t)ss[u] * D);
#pragma unroll
            for (int u = 0; u < 8; u++)
                attn_edge(w2_[u], vv[u], qv, l, a0, a1, a2, a3);
        }
        l  += __shfl_xor(l, 32, 64);
        a0 += __shfl_xor(a0, 32, 64);
        a1 += __shfl_xor(a1, 32, 64);
        a2 += __shfl_xor(a2, 32, 64);
        a3 += __shfl_xor(a3, 32, 64);
        if (lane < 32) {
            float inv = 1.f / (l + 1e-9f);
            bf16 o[4];
            o[0] = __float2bfloat16(a0 * inv);
            o[1] = __float2bfloat16(a1 * inv);
            o[2] = __float2bfloat16(a2 * inv);
            o[3] = __float2bfloat16(a3 * inv);
            *(uint2*)(out + (size_t)r * D + d0) = *(uint2*)o;
        }
    }
}

extern "C" void kernel_launch(void* const* d_in, const int* in_sizes, int n_in,
                              void* d_out, int out_size, void* d_ws, size_t ws_size,
                              hipStream_t stream) {
    const float* feat    = (const float*)d_in[0];
    const int*   senders = (const int*)d_in[1];
    const int*   recv    = (const int*)d_in[2];
    const float* enc_w1  = (const float*)d_in[3];
    const float* enc_b1  = (const float*)d_in[4];
    const float* enc_w2  = (const float*)d_in[5];
    const float* enc_b2  = (const float*)d_in[6];
    const float* wq      = (const float*)d_in[7];
    const float* wk      = (const float*)d_in[8];
    const float* wv      = (const float*)d_in[9];
    const float* wo      = (const float*)d_in[10];
    const float* ln1_s   = (const float*)d_in[11];
    const float* ln1_b   = (const float*)d_in[12];
    const float* ffn_w1  = (const float*)d_in[13];
    const float* ffn_b1  = (const float*)d_in[14];
    const float* ffn_w2  = (const float*)d_in[15];
    const float* ffn_b2  = (const float*)d_in[16];
    const float* ln2_s   = (const float*)d_in[17];
    const float* ln2_b   = (const float*)d_in[18];
    const float* dec_w1  = (const float*)d_in[19];
    const float* dec_b1  = (const float*)d_in[20];
    const float* dec_w2  = (const float*)d_in[21];
    const float* dec_b2  = (const float*)d_in[22];

    int N = in_sizes[0] / DIN;
    int E = in_sizes[1];

    // workspace layout
    char* p = (char*)d_ws;
    float* x   = (float*)p;  p += (size_t)N * D * 4;        // residual fp32
    bf16*  qb  = (bf16*)p;   p += (size_t)N * D * 2;        // q bf16 (pre-scaled)
    bf16*  kvb = (bf16*)p;   p += (size_t)N * D * 2 * 2;    // (k,v) bf16 interleaved
    bf16*  hb  = (bf16*)p;   p += (size_t)N * D * 2;        // LN out / attn out bf16
    int* deg   = (int*)p;    p += (size_t)N * 4;
    int* eid   = (int*)p;    p += (size_t)N * MAXDEG * 4;
    bf16* wqkvT  = (bf16*)p; p += (size_t)4 * 3 * D * D * 2;
    bf16* woT    = (bf16*)p; p += (size_t)4 * D * D * 2;
    bf16* w1T    = (bf16*)p; p += (size_t)4 * D * DFF * 2;
    bf16* w2T    = (bf16*)p; p += (size_t)4 * DFF * D * 2;
    bf16* encw2T = (bf16*)p; p += (size_t)D * D * 2;

    int gm64 = (N + 63) / 64;     // 782
    int gmQ  = (N + BMQ - 1) / BMQ; // 391

    k_wt<<<dim3(256, 26), 256, 0, stream>>>(wq, wk, wv, wo, ffn_w1, ffn_w2, enc_w2,
                                            wqkvT, woT, w1T, w2T, encw2T, deg, eid, N);
    k_fill<<<(E + 255) / 256, 256, 0, stream>>>(recv, senders, deg, eid, E);
    k_enc1<<<(N + TN - 1) / TN, 128, 0, stream>>>(feat, enc_w1, enc_b1, hb, N);
    // x = hb @ enc_w2 + b2; hb = LN1_0(x)
    k_gemm<5><<<gm64, 256, 0, stream>>>(hb, encw2T, enc_b2, ln1_s, ln1_b, x, hb, N);

    for (int l = 0; l < 4; l++) {
        k_qkv<<<gmQ, 512, 0, stream>>>(hb, wqkvT + (size_t)l * 3 * D * D, qb, kvb, N);
        k_attn<<<(N + 15) / 16, 256, 0, stream>>>(qb, (const uint*)kvb, deg, eid, hb, N);
        // x += hb @ wo; hb = LN2(x)
        k_gemm<2><<<gm64, 256, 0, stream>>>(hb, woT + (size_t)l * D * D,
                                            nullptr, ln2_s + l * D, ln2_b + l * D,
                                            x, hb, N);
        // x += relu(hb@w1+b1)@w2 + b2; then LN1_{l+1} (l<3) or fused decode (l=3)
        if (l < 3)
            k_ffn<0><<<gm64, 256, 0, stream>>>(hb, w1T + (size_t)l * D * DFF,
                                               ffn_b1 + l * DFF,
                                               w2T + (size_t)l * DFF * D, ffn_b2 + l * D,
                                               ln1_s + (l + 1) * D, ln1_b + (l + 1) * D,
                                               nullptr, nullptr, nullptr, nullptr,
                                               x, hb, nullptr, N);
        else
            k_ffn<1><<<gm64, 256, 0, stream>>>(hb, w1T + (size_t)l * D * DFF,
                                               ffn_b1 + l * DFF,
                                               w2T + (size_t)l * DFF * D, ffn_b2 + l * D,
                                               nullptr, nullptr,
                                               dec_w1, dec_b1, dec_w2, dec_b2,
                                               x, nullptr, (float*)d_out, N);
    }
}

// Round 7
// 619.255 us; speedup vs baseline: 1.0452x; 1.0404x over previous
//
#include <hip/hip_runtime.h>
#include <hip/hip_bf16.h>
#include <math.h>

#define D     128
#define NHEAD 4
#define DH    32
#define DFF   512
#define DIN   16
#define MAXDEG 64
#define TN    16

typedef __attribute__((ext_vector_type(8))) short bf16x8;
typedef __attribute__((ext_vector_type(4))) float f32x4;
typedef __hip_bfloat16 bf16;

// 1/sqrt(32) * log2(e): q pre-scaled so attn weight = exp2(q.k)
#define QSCALE_L2E 0.2550348838f

// r13: A-fragments in 16 VGPRs straight from global; best dense config.
// r16: dispatch/traffic elimination outside inner loops works (+22 µs).
// r18: dense kernels rebuilt on global_load_lds + raw s_barrier + counted
//      vmcnt + XOR-swizzled linear LDS. 728->641 µs.
// r19: attn shfl-broadcast of CSR row REGRESSED (bpermute serial chain).
// r20/r21: SPILL RULE: launch_bounds 2nd arg >=4 -> 64-VGPR cap -> spill.
//      (512,2)=88 VGPR clean; plain (256)=104-128 VGPR clean.
// r22/r23: k_ffn 256t quarter-stage ring-3 depth-2; clean (VGPR 104, no
//      scratch) but PINNED at ~50 µs across 3 occupancy configs: ~3.7k
//      cy/stage vs ~300 cy of work -> per-stage exposed round trip.
// r24 (this round): k_ffn depth-2 -> depth-4 (ring-6, 48 KB) + single
//      barrier per stage (ring cushion makes the slot-free barrier
//      redundant: issuer of s+4 writes slot (s-2)%6, read 2 barriers ago).
//      WAITV(8) steady (2 ops x 4 younger stages; safe under in-order
//      vmcnt retirement regardless of older-op count). x-prefetch moved
//      after final barrier (old s==15 placement drained inside WAITV(0)).
//      DIAGNOSTIC: no move => per-CU staging throughput ceiling => next
//      lever is fewer staged bytes (BM=128 / fp8), not scheduling.
#define BMQ 128

#define WAITV(N) asm volatile("s_waitcnt vmcnt(" #N ")" ::: "memory")
#define WAITLGKM asm volatile("s_waitcnt lgkmcnt(0)" ::: "memory")
#define FENCE()  asm volatile("" ::: "memory")
#define BAR() do { FENCE(); __builtin_amdgcn_s_barrier(); FENCE(); } while (0)

__device__ __forceinline__ void gll16(const bf16* g, bf16* l) {
    __builtin_amdgcn_global_load_lds((__attribute__((address_space(1))) void*)g,
                                     (__attribute__((address_space(3))) void*)l,
                                     16, 0, 0);
}

__device__ __forceinline__ ushort bfbits(float f) {
    __hip_bfloat16 b = __float2bfloat16(f);
    return *(ushort*)&b;
}

// ---------------- CSR fill (deg+eid zeroed by k_wt region 25) ---------------
__global__ void k_fill(const int* __restrict__ recv, const int* __restrict__ senders,
                       int* __restrict__ deg, int* __restrict__ eid, int E) {
    int e = blockIdx.x * blockDim.x + threadIdx.x;
    if (e >= E) return;
    int r = recv[e];
    int pos = atomicAdd(&deg[r], 1);
    if (pos < MAXDEG) eid[r * MAXDEG + pos] = senders[e];
}

// ------- weight transpose + bf16 convert + deg/eid zero (26 regions) --------
__global__ void k_wt(const float* __restrict__ wq, const float* __restrict__ wk,
                     const float* __restrict__ wv, const float* __restrict__ wo,
                     const float* __restrict__ w1, const float* __restrict__ w2,
                     const float* __restrict__ encw2,
                     bf16* __restrict__ wqkvT, bf16* __restrict__ woT,
                     bf16* __restrict__ w1T, bf16* __restrict__ w2T,
                     bf16* __restrict__ encw2T, int* __restrict__ deg,
                     int* __restrict__ eid, int N) {
    int r = blockIdx.y;
    if (r == 25) {      // zero deg + eid (runs before k_fill; eid zeroing
                        // makes stale-index loads in k_attn safe)
        int tot = N + N * MAXDEG;
        for (int i = blockIdx.x * blockDim.x + threadIdx.x; i < tot;
             i += 256 * 256) {
            if (i < N) deg[i] = 0;
            else eid[i - N] = 0;
        }
        return;
    }
    const float* src; bf16* dst; int K, Nout;
    if (r < 12) {
        int l = r / 3, sel = r % 3;
        src = (sel == 0 ? wq : sel == 1 ? wk : wv) + (size_t)l * D * D;
        dst = wqkvT + (size_t)l * 3 * D * D + (size_t)sel * D * D;
        K = D; Nout = D;
    } else if (r < 16) {
        int l = r - 12;
        src = wo + (size_t)l * D * D; dst = woT + (size_t)l * D * D; K = D; Nout = D;
    } else if (r < 20) {
        int l = r - 16;
        src = w1 + (size_t)l * D * DFF; dst = w1T + (size_t)l * D * DFF; K = D; Nout = DFF;
    } else if (r < 24) {
        int l = r - 20;
        src = w2 + (size_t)l * DFF * D; dst = w2T + (size_t)l * DFF * D; K = DFF; Nout = D;
    } else {
        src = encw2; dst = encw2T; K = D; Nout = D;
    }
    int total = K * Nout;
    int i = blockIdx.x * blockDim.x + threadIdx.x;
    if (i >= total) return;
    int k = i / Nout, j = i % Nout;
    dst[(size_t)j * K + k] = __float2bfloat16(src[i]);
}

// helper: load this wave's 4 A-fragments (16 rows x 128 cols) from global
__device__ __forceinline__ void load_afrag(const bf16* A, int arow, int quad,
                                           int N, bf16x8* afr) {
    const bf16* ab = A + (size_t)arow * D + quad * 8;
#pragma unroll
    for (int i = 0; i < 4; i++) {
        uint4 v = make_uint4(0u, 0u, 0u, 0u);
        if (arow < N) v = *(const uint4*)(ab + i * 32);
        afr[i] = *(bf16x8*)&v;
    }
}

// ---- stage a full 128x128 tile (32KB), 256 threads: 8 gll/thread ----------
// LDS linear [128][128]; granule(16B) swizzle: LDS (r,gL) <- src (r, gL^(r&15))
__device__ __forceinline__ void stage_full256(bf16* lb, const bf16* src,
                                              int wave, int lane) {
#pragma unroll
    for (int k = 0; k < 8; k++) {
        int gidx = (wave * 8 + k) * 64 + lane;
        int r = gidx >> 4, gL = gidx & 15;
        gll16(src + (size_t)r * 128 + ((gL ^ (r & 15)) * 8),
              lb + (size_t)(wave * 8 + k) * 512);
    }
}

// ---- stage a full 128x128 tile (32KB), 512 threads: 4 gll/thread ----------
__device__ __forceinline__ void stage_full512(bf16* lb, const bf16* src,
                                              int wave, int lane) {
#pragma unroll
    for (int k = 0; k < 4; k++) {
        int gidx = (wave * 4 + k) * 64 + lane;
        int r = gidx >> 4, gL = gidx & 15;
        gll16(src + (size_t)r * 128 + ((gL ^ (r & 15)) * 8),
              lb + (size_t)(wave * 4 + k) * 512);
    }
}

// ---- stage a 128x32 quarter-tile (8KB), 256 threads: 2 gll/thread ---------
// rows 64 B: swizzle gL ^ ((r>>1)&3) spreads lanes over all 32 banks
// (2-way = free); gL ^ (r&3) would 8-way conflict.
__device__ __forceinline__ void stage_q(bf16* lb, const bf16* src, int rs,
                                        int wave, int lane) {
#pragma unroll
    for (int k = 0; k < 2; k++) {
        int gidx = (wave * 2 + k) * 64 + lane;      // 0..511
        int r = gidx >> 2, gL = gidx & 3;           // 128 rows x 4 granules
        gll16(src + (size_t)r * rs + ((gL ^ ((r >> 1) & 3)) * 8),
              lb + (size_t)(wave * 2 + k) * 512);
    }
}

// MFMA over a full swizzled tile: acc[j] += A(afr) * W[128][128]
__device__ __forceinline__ void mfma_tile(const bf16* Wb, const bf16x8* afr,
                                          f32x4* acc, int l16, int quad) {
#pragma unroll
    for (int i = 0; i < 4; i++)
#pragma unroll
        for (int j = 0; j < 8; j++) {
            const bf16* wp = Wb + (size_t)(j * 16 + l16) * 128
                              + (size_t)((((i * 4 + quad)) ^ l16) * 8);
            acc[j] = __builtin_amdgcn_mfma_f32_16x16x32_bf16(afr[i], *(const bf16x8*)wp,
                                                             acc[j], 0, 0, 0);
        }
}

// ---------------- bf16 MFMA GEMM, 64 rows x 128 cols, K=128, 256t -----------
// OPs: 2 RES_LN (wo+ln2), 5 BIAS_LN (encode+ln1_0)
template<int OP>
__global__ __launch_bounds__(256) void k_gemm(
        const bf16* __restrict__ A, const bf16* __restrict__ Bt,
        const float* __restrict__ bias,
        const float* __restrict__ lns, const float* __restrict__ lnb,
        float* x, bf16* outB, int N) {
    __shared__ alignas(16) bf16 Wsm[128 * 128];   // 32 KB -> 4 blocks/CU
    int m0 = blockIdx.x * 64;
    int t = threadIdx.x;
    int wave = t >> 6, lane = t & 63;
    int quad = lane >> 4, l16 = lane & 15;
    int wm = wave * 16;

    bf16x8 afr[4];
    load_afrag(A, m0 + wm + l16, quad, N, afr);
    FENCE();
    stage_full256(Wsm, Bt, wave, lane);
    WAITV(0); BAR();

    int rowb = m0 + wm + quad * 4;
    float xv[8][4];
    if (OP == 2) {   // hoist residual reads: latency hides under MFMA phase
#pragma unroll
        for (int j = 0; j < 8; j++)
#pragma unroll
            for (int r = 0; r < 4; r++) {
                int gr = rowb + r;
                xv[j][r] = (gr < N) ? x[(size_t)gr * D + j * 16 + l16] : 0.f;
            }
    }

    f32x4 acc[8];
#pragma unroll
    for (int j = 0; j < 8; j++) acc[j] = (f32x4){0.f, 0.f, 0.f, 0.f};
    mfma_tile(Wsm, afr, acc, l16, quad);

    float bv[8];
    if (OP == 5) {
#pragma unroll
        for (int j = 0; j < 8; j++) bv[j] = bias[j * 16 + l16];
    }
#pragma unroll
    for (int j = 0; j < 8; j++) {
#pragma unroll
        for (int r = 0; r < 4; r++) {
            int gr = rowb + r;
            if (gr >= N) continue;
            float val = acc[j][r];
            if (OP == 5) val += bv[j];
            if (OP == 2) val += xv[j][r];
            acc[j][r] = val;
        }
    }
    float lsv[8], lbv[8];
#pragma unroll
    for (int j = 0; j < 8; j++) {
        lsv[j] = lns[j * 16 + l16];
        lbv[j] = lnb[j * 16 + l16];
    }
#pragma unroll
    for (int r = 0; r < 4; r++) {
        float s1 = 0.f, s2 = 0.f;
#pragma unroll
        for (int j = 0; j < 8; j++) {
            float v = acc[j][r];
            s1 += v; s2 += v * v;
        }
        s1 += __shfl_xor(s1, 1, 64);  s2 += __shfl_xor(s2, 1, 64);
        s1 += __shfl_xor(s1, 2, 64);  s2 += __shfl_xor(s2, 2, 64);
        s1 += __shfl_xor(s1, 4, 64);  s2 += __shfl_xor(s2, 4, 64);
        s1 += __shfl_xor(s1, 8, 64);  s2 += __shfl_xor(s2, 8, 64);
        float mu = s1 * (1.f / 128.f);
        float var = s2 * (1.f / 128.f) - mu * mu;
        float rinv = rsqrtf(fmaxf(var, 0.f) + 1e-5f);
        int gr = rowb + r;
        if (gr >= N) continue;
#pragma unroll
        for (int j = 0; j < 8; j++) {
            int col = j * 16 + l16;
            float v = acc[j][r];
            x[(size_t)gr * D + col] = v;
            outB[(size_t)gr * D + col] =
                __float2bfloat16((v - mu) * rinv * lsv[j] + lbv[j]);
        }
    }
}

// ---------------- fused QKV: K->V->Q phases, <=2 live acc sets (r21) --------
__global__ __launch_bounds__(512, 2) void k_qkv(
        const bf16* __restrict__ hb, const bf16* __restrict__ wqkvT,
        bf16* __restrict__ qb, bf16* __restrict__ kvb, int N) {
    __shared__ alignas(16) bf16 Wbuf[2][128 * 128];   // 64 KB -> 2 blocks/CU
    int m0 = blockIdx.x * BMQ;
    int t = threadIdx.x;
    int wave = t >> 6, lane = t & 63;
    int quad = lane >> 4, l16 = lane & 15;
    int wm = wave * 16;

    bf16x8 afr[4];
    load_afrag(hb, m0 + wm + l16, quad, N, afr);             // 4 vm (oldest)
    FENCE();
    stage_full512(Wbuf[0], wqkvT + (size_t)D * D, wave, lane);   // K tile
    FENCE();
    stage_full512(Wbuf[1], wqkvT + (size_t)2 * D * D, wave, lane); // V tile
    FENCE();

    int rowb = m0 + wm + quad * 4;
    f32x4 ak[8], acc[8];
#pragma unroll
    for (int j = 0; j < 8; j++) ak[j] = (f32x4){0.f, 0.f, 0.f, 0.f};

    WAITV(4); BAR();                 // afr + K landed; V in flight
    __builtin_amdgcn_s_setprio(1);
    mfma_tile(Wbuf[0], afr, ak, l16, quad);
    __builtin_amdgcn_s_setprio(0);
    BAR();                           // buf0 free
    stage_full512(Wbuf[0], wqkvT, wave, lane);   // Q tile
    FENCE();
#pragma unroll
    for (int j = 0; j < 8; j++) acc[j] = (f32x4){0.f, 0.f, 0.f, 0.f};
    WAITV(4); BAR();                 // V landed; Q in flight
    __builtin_amdgcn_s_setprio(1);
    mfma_tile(Wbuf[1], afr, acc, l16, quad);   // acc = V
    __builtin_amdgcn_s_setprio(0);

    // pack + store kv now (overlaps Q-tile gll latency)
#pragma unroll
    for (int j = 0; j < 8; j++) {
        int col = j * 16 + l16;
#pragma unroll
        for (int r = 0; r < 4; r++) {
            int gr = rowb + r;
            if (gr >= N) continue;
            uint kv = (uint)bfbits(ak[j][r]) | ((uint)bfbits(acc[j][r]) << 16);
            *(uint*)&kvb[((size_t)gr * D + col) * 2] = kv;
        }
    }
    FENCE();
    if (m0 + BMQ <= N) { WAITV(32); } else { WAITV(0); }   // Q tile landed
    BAR();
#pragma unroll
    for (int j = 0; j < 8; j++) acc[j] = (f32x4){0.f, 0.f, 0.f, 0.f};
    __builtin_amdgcn_s_setprio(1);
    mfma_tile(Wbuf[0], afr, acc, l16, quad);   // acc = Q
    __builtin_amdgcn_s_setprio(0);
#pragma unroll
    for (int j = 0; j < 8; j++) {
        int col = j * 16 + l16;
#pragma unroll
        for (int r = 0; r < 4; r++) {
            int gr = rowb + r;
            if (gr >= N) continue;
            qb[(size_t)gr * D + col] = __float2bfloat16(acc[j][r] * QSCALE_L2E);
        }
    }
}

// ---- stage FFN quarter ts (0..31) into ring-6 slot ts%6 -------------------
__device__ __forceinline__ void stage_ffn_q(int ts, const bf16* w1T,
                                            const bf16* w2T, bf16* Wb6,
                                            int wave, int lane) {
    int c = ts >> 3, p = ts & 7;
    const bf16* src; int rs;
    if (p < 4) { src = w1T + (size_t)(c * 128) * 128 + p * 32;       rs = 128; }
    else       { src = w2T + (size_t)(c * 128) + (p - 4) * 32;       rs = DFF; }
    stage_q(Wb6 + (size_t)(ts % 6) * (32 * 128), src, rs, wave, lane);
}

// ------- fused FFN: 32-stage gll pipeline, depth-4, ring-6, 1 bar/stage -----
// 64 KB LDS -> 2 blocks/CU. Single barrier is safe: issuer of stage s+4
// writes slot (s-2)%6, which every wave finished reading before barrier s-1.
// x += relu(hb@w1+b1)@w2 + b2; then LN (MODE 0) or fused decode (MODE 1)
template<int MODE>
__global__ __launch_bounds__(256) void k_ffn(
        const bf16* __restrict__ hb, const bf16* __restrict__ w1T,
        const float* __restrict__ b1,
        const bf16* __restrict__ w2T, const float* __restrict__ b2,
        const float* __restrict__ lns, const float* __restrict__ lnb,
        const float* __restrict__ dw1, const float* __restrict__ db1,
        const float* __restrict__ dw2, const float* __restrict__ db2,
        float* x, bf16* outB, float* out, int N) {
    __shared__ alignas(16) bf16 Wb6[6][32 * 128];   // 48 KB ring
    __shared__ alignas(16) bf16 Hsm[64 * 128];      // 16 KB (swizzled) => 64 KB
    int m0 = blockIdx.x * 64;
    int t = threadIdx.x;
    int wave = t >> 6, lane = t & 63;
    int quad = lane >> 4, l16 = lane & 15;
    int wm = wave * 16;
    int rowb = m0 + wm + quad * 4;

    // preload all b1 biases: keeps the pipeline free of stray vmem ops
    float b1pre[4][8];
#pragma unroll
    for (int c2 = 0; c2 < 4; c2++)
#pragma unroll
        for (int j = 0; j < 8; j++) b1pre[c2][j] = b1[c2 * 128 + j * 16 + l16];

    bf16x8 afr[4];
    load_afrag(hb, m0 + wm + l16, quad, N, afr);
    FENCE();
    stage_ffn_q(0, w1T, w2T, &Wb6[0][0], wave, lane); FENCE();
    stage_ffn_q(1, w1T, w2T, &Wb6[0][0], wave, lane); FENCE();
    stage_ffn_q(2, w1T, w2T, &Wb6[0][0], wave, lane); FENCE();
    stage_ffn_q(3, w1T, w2T, &Wb6[0][0], wave, lane); FENCE();

    f32x4 acc2[8], accP[8];
#pragma unroll
    for (int j = 0; j < 8; j++) acc2[j] = (f32x4){0.f, 0.f, 0.f, 0.f};
    float xv[8][4];

    int wswz = (quad ^ ((l16 >> 1) & 3)) * 8;   // W quarter-granule swizzle

#pragma unroll
    for (int s = 0; s < 32; s++) {
        if (s + 4 < 32) {
            stage_ffn_q(s + 4, w1T, w2T, &Wb6[0][0], wave, lane);
            FENCE();
        }
        // wait for stage s: younger ops = 2 per still-in-flight stage.
        // Counts are lower bounds on younger ops only -> safe even if
        // older ops (b1pre/afr) linger (in-order vmcnt retirement).
        if (s < 28)       { WAITV(8); }
        else if (s == 28) { WAITV(6); }
        else if (s == 29) { WAITV(4); }
        else if (s == 30) { WAITV(2); }
        else              { WAITV(0); }
        BAR();                       // stage-s data visible to all waves
        if (s == 31) {   // residual prefetch: overlaps last W2 quarter
#pragma unroll
            for (int j = 0; j < 8; j++)
#pragma unroll
                for (int r = 0; r < 4; r++) {
                    int gr = min(rowb + r, N - 1);   // clamped: unconditional
                    xv[j][r] = x[(size_t)gr * D + j * 16 + l16];
                }
            FENCE();
        }
        const bf16* Wb = &Wb6[0][0] + (size_t)(s % 6) * (32 * 128);
        int c = s >> 3, p = s & 7;
        if (p < 4) {
            if (p == 0) {
#pragma unroll
                for (int j = 0; j < 8; j++) accP[j] = (f32x4){0.f, 0.f, 0.f, 0.f};
            }
            __builtin_amdgcn_s_setprio(1);
#pragma unroll
            for (int j = 0; j < 8; j++) {
                const bf16* wp = Wb + (size_t)(j * 16 + l16) * 32 + wswz;
                accP[j] = __builtin_amdgcn_mfma_f32_16x16x32_bf16(
                    afr[p], *(const bf16x8*)wp, accP[j], 0, 0, 0);
            }
            __builtin_amdgcn_s_setprio(0);
            if (p == 3) {   // relu+bias -> swizzled Hsm (wave-private rows)
                int rw = wm + quad * 4;
#pragma unroll
                for (int j = 0; j < 8; j++) {
                    int gb = j * 2 + (l16 >> 3), ce = l16 & 7;
#pragma unroll
                    for (int r = 0; r < 4; r++) {
                        int row = rw + r;
                        Hsm[(size_t)row * 128 + (size_t)((gb ^ (row & 15)) * 8) + ce] =
                            __float2bfloat16(fmaxf(accP[j][r] + b1pre[c][j], 0.f));
                    }
                }
                WAITLGKM;   // own ds_writes drained before next barrier
            }
        } else {
            int kq = p - 4;
            bf16x8 af2 = *(const bf16x8*)(Hsm + (size_t)(wm + l16) * 128
                              + (size_t)(((kq * 4 + quad) ^ l16) * 8));
            __builtin_amdgcn_s_setprio(1);
#pragma unroll
            for (int j = 0; j < 8; j++) {
                const bf16* wp = Wb + (size_t)(j * 16 + l16) * 32 + wswz;
                acc2[j] = __builtin_amdgcn_mfma_f32_16x16x32_bf16(
                    af2, *(const bf16x8*)wp, acc2[j], 0, 0, 0);
            }
            __builtin_amdgcn_s_setprio(0);
        }
    }
    WAITV(0);   // xv landed
    FENCE();

    float bv[8];
#pragma unroll
    for (int j = 0; j < 8; j++) bv[j] = b2[j * 16 + l16];
#pragma unroll
    for (int j = 0; j < 8; j++) {
#pragma unroll
        for (int r = 0; r < 4; r++) {
            int gr = rowb + r;
            if (gr >= N) continue;
            acc2[j][r] += bv[j] + xv[j][r];
        }
    }
    if (MODE == 1) {
        float dw[8][3];
#pragma unroll
        for (int j = 0; j < 8; j++) {
            int col = j * 16 + l16;
#pragma unroll
            for (int cc3 = 0; cc3 < 3; cc3++) dw[j][cc3] = dw1[col * 3 + cc3];
        }
#pragma unroll
        for (int r = 0; r < 4; r++) {
            float s0 = 0.f, s1 = 0.f, s2 = 0.f;
#pragma unroll
            for (int j = 0; j < 8; j++) {
                float v = acc2[j][r];
                s0 += v * dw[j][0]; s1 += v * dw[j][1]; s2 += v * dw[j][2];
            }
            s0 += __shfl_xor(s0, 1, 64); s1 += __shfl_xor(s1, 1, 64); s2 += __shfl_xor(s2, 1, 64);
            s0 += __shfl_xor(s0, 2, 64); s1 += __shfl_xor(s1, 2, 64); s2 += __shfl_xor(s2, 2, 64);
            s0 += __shfl_xor(s0, 4, 64); s1 += __shfl_xor(s1, 4, 64); s2 += __shfl_xor(s2, 4, 64);
            s0 += __shfl_xor(s0, 8, 64); s1 += __shfl_xor(s1, 8, 64); s2 += __shfl_xor(s2, 8, 64);
            int gr = rowb + r;
            if (l16 == 0 && gr < N) {
                float t0 = fmaxf(s0 + db1[0], 0.f);
                float t1 = fmaxf(s1 + db1[1], 0.f);
                float t2 = fmaxf(s2 + db1[2], 0.f);
#pragma unroll
                for (int o = 0; o < 3; o++)
                    out[(size_t)gr * 3 + o] =
                        t0 * dw2[0 * 3 + o] + t1 * dw2[1 * 3 + o] + t2 * dw2[2 * 3 + o] + db2[o];
            }
        }
        return;
    }
    float lsv[8], lbv[8];
#pragma unroll
    for (int j = 0; j < 8; j++) {
        lsv[j] = lns[j * 16 + l16];
        lbv[j] = lnb[j * 16 + l16];
    }
#pragma unroll
    for (int r = 0; r < 4; r++) {
        float s1 = 0.f, s2 = 0.f;
#pragma unroll
        for (int j = 0; j < 8; j++) {
            float v = acc2[j][r];
            s1 += v; s2 += v * v;
        }
        s1 += __shfl_xor(s1, 1, 64);  s2 += __shfl_xor(s2, 1, 64);
        s1 += __shfl_xor(s1, 2, 64);  s2 += __shfl_xor(s2, 2, 64);
        s1 += __shfl_xor(s1, 4, 64);  s2 += __shfl_xor(s2, 4, 64);
        s1 += __shfl_xor(s1, 8, 64);  s2 += __shfl_xor(s2, 8, 64);
        float mu = s1 * (1.f / 128.f);
        float var = s2 * (1.f / 128.f) - mu * mu;
        float rinv = rsqrtf(fmaxf(var, 0.f) + 1e-5f);
        int gr = rowb + r;
        if (gr >= N) continue;
#pragma unroll
        for (int j = 0; j < 8; j++) {
            int col = j * 16 + l16;
            float v = acc2[j][r];
            x[(size_t)gr * D + col] = v;
            outB[(size_t)gr * D + col] = __float2bfloat16((v - mu) * rinv * lsv[j] + lbv[j]);
        }
    }
}

// ---------------- encoder stage 1: hb = bf16(relu(f@w1+b1)) ----------------
__global__ void k_enc1(const float* __restrict__ feat,
                       const float* __restrict__ w1, const float* __restrict__ b1,
                       bf16* __restrict__ hb, int N) {
    __shared__ float fsh[TN][DIN];
    int n0 = blockIdx.x * TN;
    int j = threadIdx.x;            // 0..127
    int nvalid = min(TN, N - n0);
    for (int idx = j; idx < TN * DIN; idx += 128) {
        int n = idx / DIN, i = idx % DIN;
        fsh[n][i] = (n < nvalid) ? feat[(n0 + n) * DIN + i] : 0.f;
    }
    __syncthreads();
    float bb = b1[j];
#pragma unroll
    for (int n = 0; n < TN; n++) {
        float a = bb;
#pragma unroll
        for (int i = 0; i < DIN; i++) a += fsh[n][i] * w1[i * D + j];
        if (n < nvalid) hb[(size_t)(n0 + n) * D + j] = __float2bfloat16(fmaxf(a, 0.f));
    }
}

// ---------------- attention: 4 receivers/wave, cross-receiver prefetch ------
// eid is zero-initialized -> index loads are unconditional/safe; next
// receiver's {indices, deg, q} load while current receiver's kv gathers are
// in flight, removing the deg->idx->gather serial chain from steady state.
__device__ __forceinline__ void attn_edge(uint4 w, bool v, float4 qv,
                                          float& l, float& a0, float& a1,
                                          float& a2, float& a3) {
    float k0 = __uint_as_float(w.x << 16), v0 = __uint_as_float(w.x & 0xFFFF0000u);
    float k1 = __uint_as_float(w.y << 16), v1 = __uint_as_float(w.y & 0xFFFF0000u);
    float k2 = __uint_as_float(w.z << 16), v2 = __uint_as_float(w.z & 0xFFFF0000u);
    float k3 = __uint_as_float(w.w << 16), v3 = __uint_as_float(w.w & 0xFFFF0000u);
    float p = qv.x * k0 + qv.y * k1 + qv.z * k2 + qv.w * k3;
    p += __shfl_xor(p, 1, 64);
    p += __shfl_xor(p, 2, 64);
    p += __shfl_xor(p, 4, 64);
    float e = v ? exp2f(p) : 0.f;
    l += e;
    a0 += e * v0; a1 += e * v1; a2 += e * v2; a3 += e * v3;
}

__device__ __forceinline__ float4 unpackq(uint2 qw) {
    float4 qv;
    qv.x = __uint_as_float(qw.x << 16);
    qv.y = __uint_as_float(qw.x & 0xFFFF0000u);
    qv.z = __uint_as_float(qw.y << 16);
    qv.w = __uint_as_float(qw.y & 0xFFFF0000u);
    return qv;
}

__global__ __launch_bounds__(256) void k_attn(
        const bf16* __restrict__ qb, const uint* __restrict__ kvb,
        const int* __restrict__ deg, const int* __restrict__ eid,
        bf16* __restrict__ out, int N) {
    int wave = threadIdx.x >> 6, lane = threadIdx.x & 63;
    int g = lane & 7, h = (lane >> 3) & 3, slot = lane >> 5;
    int d0 = h * 32 + g * 4;
    int rbase = blockIdx.x * 16 + wave * 4;
    if (rbase >= N) return;
    const uint* kvbase = kvb + d0;

    // ctx for first receiver
    int ssN[8];
    {
        const int* row = eid + (size_t)rbase * MAXDEG;
#pragma unroll
        for (int u = 0; u < 8; u++) ssN[u] = row[u * 2 + slot];
    }
    int cntN = min(deg[rbase], MAXDEG);
    float4 qvN = unpackq(*(const uint2*)(qb + (size_t)rbase * D + d0));

#pragma unroll
    for (int i = 0; i < 4; i++) {
        int r = rbase + i;
        if (r >= N) return;
        int cnt = cntN; float4 qv = qvN;
        // issue first-16 gathers immediately (addresses safe: eid zeroed)
        uint4 w[8];
#pragma unroll
        for (int u = 0; u < 8; u++)
            w[u] = *(const uint4*)(kvbase + (size_t)ssN[u] * D);
        // prefetch next receiver's ctx (overlaps the gathers)
        int rn = r + 1;
        if (i < 3 && rn < N) {
            const int* rowN = eid + (size_t)rn * MAXDEG;
#pragma unroll
            for (int u = 0; u < 8; u++) ssN[u] = rowN[u * 2 + slot];
            cntN = min(deg[rn], MAXDEG);
            qvN = unpackq(*(const uint2*)(qb + (size_t)rn * D + d0));
        }
        float l = 0.f, a0 = 0.f, a1 = 0.f, a2 = 0.f, a3 = 0.f;
#pragma unroll
        for (int u = 0; u < 8; u++)
            attn_edge(w[u], (u * 2 + slot) < cnt, qv, l, a0, a1, a2, a3);
        for (int base = 16; base < cnt; base += 16) {   // rare (deg>16)
            const int* row = eid + (size_t)r * MAXDEG;
            int ss[8]; bool vv[8];
#pragma unroll
            for (int u = 0; u < 8; u++) {
                int e = base + u * 2 + slot;
                vv[u] = e < cnt;
                ss[u] = row[e];            // e<64, zero-inited -> safe
            }
            uint4 w2_[8];
#pragma unroll
            for (int u = 0; u < 8; u++)
                w2_[u] = *(const uint4*)(kvbase + (size_t)ss[u] * D);
#pragma unroll
            for (int u = 0; u < 8; u++)
                attn_edge(w2_[u], vv[u], qv, l, a0, a1, a2, a3);
        }
        l  += __shfl_xor(l, 32, 64);
        a0 += __shfl_xor(a0, 32, 64);
        a1 += __shfl_xor(a1, 32, 64);
        a2 += __shfl_xor(a2, 32, 64);
        a3 += __shfl_xor(a3, 32, 64);
        if (lane < 32) {
            float inv = 1.f / (l + 1e-9f);
            bf16 o[4];
            o[0] = __float2bfloat16(a0 * inv);
            o[1] = __float2bfloat16(a1 * inv);
            o[2] = __float2bfloat16(a2 * inv);
            o[3] = __float2bfloat16(a3 * inv);
            *(uint2*)(out + (size_t)r * D + d0) = *(uint2*)o;
        }
    }
}

extern "C" void kernel_launch(void* const* d_in, const int* in_sizes, int n_in,
                              void* d_out, int out_size, void* d_ws, size_t ws_size,
                              hipStream_t stream) {
    const float* feat    = (const float*)d_in[0];
    const int*   senders = (const int*)d_in[1];
    const int*   recv    = (const int*)d_in[2];
    const float* enc_w1  = (const float*)d_in[3];
    const float* enc_b1  = (const float*)d_in[4];
    const float* enc_w2  = (const float*)d_in[5];
    const float* enc_b2  = (const float*)d_in[6];
    const float* wq      = (const float*)d_in[7];
    const float* wk      = (const float*)d_in[8];
    const float* wv      = (const float*)d_in[9];
    const float* wo      = (const float*)d_in[10];
    const float* ln1_s   = (const float*)d_in[11];
    const float* ln1_b   = (const float*)d_in[12];
    const float* ffn_w1  = (const float*)d_in[13];
    const float* ffn_b1  = (const float*)d_in[14];
    const float* ffn_w2  = (const float*)d_in[15];
    const float* ffn_b2  = (const float*)d_in[16];
    const float* ln2_s   = (const float*)d_in[17];
    const float* ln2_b   = (const float*)d_in[18];
    const float* dec_w1  = (const float*)d_in[19];
    const float* dec_b1  = (const float*)d_in[20];
    const float* dec_w2  = (const float*)d_in[21];
    const float* dec_b2  = (const float*)d_in[22];

    int N = in_sizes[0] / DIN;
    int E = in_sizes[1];

    // workspace layout
    char* p = (char*)d_ws;
    float* x   = (float*)p;  p += (size_t)N * D * 4;        // residual fp32
    bf16*  qb  = (bf16*)p;   p += (size_t)N * D * 2;        // q bf16 (pre-scaled)
    bf16*  kvb = (bf16*)p;   p += (size_t)N * D * 2 * 2;    // (k,v) bf16 interleaved
    bf16*  hb  = (bf16*)p;   p += (size_t)N * D * 2;        // LN out / attn out bf16
    int* deg   = (int*)p;    p += (size_t)N * 4;
    int* eid   = (int*)p;    p += (size_t)N * MAXDEG * 4;
    bf16* wqkvT  = (bf16*)p; p += (size_t)4 * 3 * D * D * 2;
    bf16* woT    = (bf16*)p; p += (size_t)4 * D * D * 2;
    bf16* w1T    = (bf16*)p; p += (size_t)4 * D * DFF * 2;
    bf16* w2T    = (bf16*)p; p += (size_t)4 * DFF * D * 2;
    bf16* encw2T = (bf16*)p; p += (size_t)D * D * 2;

    int gm64 = (N + 63) / 64;     // 782
    int gmQ  = (N + BMQ - 1) / BMQ; // 391

    k_wt<<<dim3(256, 26), 256, 0, stream>>>(wq, wk, wv, wo, ffn_w1, ffn_w2, enc_w2,
                                            wqkvT, woT, w1T, w2T, encw2T, deg, eid, N);
    k_fill<<<(E + 255) / 256, 256, 0, stream>>>(recv, senders, deg, eid, E);
    k_enc1<<<(N + TN - 1) / TN, 128, 0, stream>>>(feat, enc_w1, enc_b1, hb, N);
    // x = hb @ enc_w2 + b2; hb = LN1_0(x)
    k_gemm<5><<<gm64, 256, 0, stream>>>(hb, encw2T, enc_b2, ln1_s, ln1_b, x, hb, N);

    for (int l = 0; l < 4; l++) {
        k_qkv<<<gmQ, 512, 0, stream>>>(hb, wqkvT + (size_t)l * 3 * D * D, qb, kvb, N);
        k_attn<<<(N + 15) / 16, 256, 0, stream>>>(qb, (const uint*)kvb, deg, eid, hb, N);
        // x += hb @ wo; hb = LN2(x)
        k_gemm<2><<<gm64, 256, 0, stream>>>(hb, woT + (size_t)l * D * D,
                                            nullptr, ln2_s + l * D, ln2_b + l * D,
                                            x, hb, N);
        // x += relu(hb@w1+b1)@w2 + b2; then LN1_{l+1} (l<3) or fused decode (l=3)
        if (l < 3)
            k_ffn<0><<<gm64, 256, 0, stream>>>(hb, w1T + (size_t)l * D * DFF,
                                               ffn_b1 + l * DFF,
                                               w2T + (size_t)l * DFF * D, ffn_b2 + l * D,
                                               ln1_s + (l + 1) * D, ln1_b + (l + 1) * D,
                                               nullptr, nullptr, nullptr, nullptr,
                                               x, hb, nullptr, N);
        else
            k_ffn<1><<<gm64, 256, 0, stream>>>(hb, w1T + (size_t)l * D * DFF,
                                               ffn_b1 + l * DFF,
                                               w2T + (size_t)l * DFF * D, ffn_b2 + l * D,
                                               nullptr, nullptr,
                                               dec_w1, dec_b1, dec_w2, dec_b2,
                                               x, nullptr, (float*)d_out, N);
    }
}